// Round 1
// baseline (1651.768 us; speedup 1.0000x reference)
//
#include <hip/hip_runtime.h>
#include <math.h>

#define NN 50000
#define EE 800000
#define HH 256
#define CC 64
#define ETT 3
#define EFF 20
#define CH 8192   // row chunk for the [CH, 4H] gelu intermediate

__device__ __forceinline__ float gelu_f(float x) {
    const float k0 = 0.7978845608028654f; // sqrt(2/pi)
    float x3 = x * x * x;
    return 0.5f * x * (1.0f + tanhf(k0 * (x + 0.044715f * x3)));
}

// C[M,Nc] = act(A[M,K] @ W[K,Nc] + bias); A,W,C row-major. K%16==0, Nc%64==0.
template<bool GELU>
__global__ __launch_bounds__(256) void gemm_bias_act(
    const float* __restrict__ A, const float* __restrict__ W,
    const float* __restrict__ bias, float* __restrict__ C,
    int M, int K, int Nc)
{
    __shared__ float As[16][68];   // [k][row], padded for 16B-aligned b128 reads
    __shared__ float Ws[16][68];   // [k][col]
    const int t  = threadIdx.x;
    const int tx = t & 15, ty = t >> 4;
    const int row0 = blockIdx.y * 64;
    const int col0 = blockIdx.x * 64;

    float acc[4][4] = {};
    const int ar = t >> 2;          // 0..63 row within tile
    const int ak = (t & 3) * 4;     // 0,4,8,12 k within tile
    const int wr = t >> 4;          // 0..15 k within tile
    const int wc = (t & 15) * 4;    // 0..60 col within tile

    for (int k0 = 0; k0 < K; k0 += 16) {
        float4 av = make_float4(0.f, 0.f, 0.f, 0.f);
        int arow = row0 + ar;
        if (arow < M)
            av = *reinterpret_cast<const float4*>(&A[(size_t)arow * K + k0 + ak]);
        As[ak + 0][ar] = av.x; As[ak + 1][ar] = av.y;
        As[ak + 2][ar] = av.z; As[ak + 3][ar] = av.w;

        float4 wv = *reinterpret_cast<const float4*>(&W[(size_t)(k0 + wr) * Nc + col0 + wc]);
        Ws[wr][wc + 0] = wv.x; Ws[wr][wc + 1] = wv.y;
        Ws[wr][wc + 2] = wv.z; Ws[wr][wc + 3] = wv.w;
        __syncthreads();

        #pragma unroll
        for (int k = 0; k < 16; ++k) {
            float a_[4], w_[4];
            #pragma unroll
            for (int i = 0; i < 4; ++i) a_[i] = As[k][ty * 4 + i];
            #pragma unroll
            for (int j = 0; j < 4; ++j) w_[j] = Ws[k][tx * 4 + j];
            #pragma unroll
            for (int i = 0; i < 4; ++i)
                #pragma unroll
                for (int j = 0; j < 4; ++j)
                    acc[i][j] += a_[i] * w_[j];
        }
        __syncthreads();
    }

    #pragma unroll
    for (int i = 0; i < 4; ++i) {
        int r = row0 + ty * 4 + i;
        if (r >= M) continue;
        #pragma unroll
        for (int j = 0; j < 4; ++j) {
            int c = col0 + tx * 4 + j;
            float v = acc[i][j] + bias[c];
            if (GELU) v = gelu_f(v);
            C[(size_t)r * Nc + c] = v;
        }
    }
}

// LayerNorm in-place over rows of h [N, 256]; one block (256 thr) per row.
__global__ __launch_bounds__(256) void ln_kernel(
    float* __restrict__ h, const float* __restrict__ g, const float* __restrict__ b)
{
    int row = blockIdx.x;
    int t = threadIdx.x;
    float x = h[(size_t)row * HH + t];
    float s1 = x, s2 = x * x;
    #pragma unroll
    for (int off = 32; off; off >>= 1) {
        s1 += __shfl_down(s1, off);
        s2 += __shfl_down(s2, off);
    }
    __shared__ float r1[4], r2[4];
    int wid = t >> 6;
    if ((t & 63) == 0) { r1[wid] = s1; r2[wid] = s2; }
    __syncthreads();
    if (t == 0) {
        float a = 0.f, bb = 0.f;
        #pragma unroll
        for (int i = 0; i < 4; ++i) { a += r1[i]; bb += r2[i]; }
        r1[0] = a; r2[0] = bb;
    }
    __syncthreads();
    float mean = r1[0] * (1.0f / HH);
    float var  = r2[0] * (1.0f / HH) - mean * mean;
    float xn = (x - mean) * rsqrtf(var + 1e-5f);
    h[(size_t)row * HH + t] = xn * g[t] + b[t];
}

// k2 per edge-type: k2t[t][h] = gelu(emb_table[t]) @ We + be   (3 x 256)
__global__ void k2_kernel(const float* __restrict__ emb_table,
                          const float* __restrict__ We, const float* __restrict__ be,
                          float* __restrict__ k2t)
{
    int ty = blockIdx.x;      // 0..ET-1
    int hc = threadIdx.x;     // 0..255
    float acc = be[hc];
    #pragma unroll
    for (int f = 0; f < EFF; ++f)
        acc += gelu_f(emb_table[ty * EFF + f]) * We[f * HH + hc];
    k2t[ty * HH + hc] = acc;
}

__global__ void init_m_kernel(float* __restrict__ m) {
    int i = blockIdx.x * 256 + threadIdx.x;
    if (i < NN) m[i] = -INFINITY;
}

// Per-edge alpha = <q[dst], k1[src] + k2t[type]> / 16, plus segment max into m.
// 16 lanes per edge.
__global__ __launch_bounds__(256) void edge_alpha_kernel(
    const float* __restrict__ q, const float* __restrict__ k1,
    const float* __restrict__ k2t, const int* __restrict__ src,
    const int* __restrict__ dst, const int* __restrict__ typ,
    float* __restrict__ alpha, float* __restrict__ m)
{
    int t = threadIdx.x;
    int e = blockIdx.x * 16 + (t >> 4);
    int lane = t & 15;
    if (e >= EE) return;
    int s_ = src[e], d_ = dst[e], ty_ = typ[e];
    const float4* q4 = reinterpret_cast<const float4*>(q  + (size_t)d_ * HH);
    const float4* k4 = reinterpret_cast<const float4*>(k1 + (size_t)s_ * HH);
    const float4* e4 = reinterpret_cast<const float4*>(k2t + (size_t)ty_ * HH);
    float acc = 0.f;
    #pragma unroll
    for (int stp = 0; stp < 4; ++stp) {
        int f = stp * 16 + lane;
        float4 qv = q4[f], kv = k4[f], ev = e4[f];
        acc += qv.x * (kv.x + ev.x) + qv.y * (kv.y + ev.y)
             + qv.z * (kv.z + ev.z) + qv.w * (kv.w + ev.w);
    }
    acc += __shfl_xor(acc, 8);
    acc += __shfl_xor(acc, 4);
    acc += __shfl_xor(acc, 2);
    acc += __shfl_xor(acc, 1);
    if (lane == 0) {
        float a = acc * 0.0625f;   // 1/sqrt(256)
        alpha[e] = a;
        if (a >= 0.f) atomicMax((int*)&m[d_], __float_as_int(a));
        else          atomicMin((unsigned int*)&m[d_], __float_as_uint(a));
    }
}

// e = exp(alpha - m[dst]); alpha <- e; s[dst] += e
__global__ void edge_exp_kernel(float* __restrict__ alpha, const int* __restrict__ dst,
                                const float* __restrict__ m, float* __restrict__ s)
{
    int e = blockIdx.x * 256 + threadIdx.x;
    if (e >= EE) return;
    int d_ = dst[e];
    float ex = expf(alpha[e] - m[d_]);
    alpha[e] = ex;
    atomicAdd(&s[d_], ex);
}

// out[dst] += scores[src] * (e / s[dst]); 64 lanes per edge (one per channel)
__global__ __launch_bounds__(256) void edge_scatter_kernel(
    const float* __restrict__ alpha, const int* __restrict__ src,
    const int* __restrict__ dst, const float* __restrict__ s,
    const float* __restrict__ scores, float* __restrict__ out)
{
    int t = threadIdx.x;
    int e = blockIdx.x * 4 + (t >> 6);
    int c = t & 63;
    if (e >= EE) return;
    int s_ = src[e], d_ = dst[e];
    float a = alpha[e] / s[d_];
    atomicAdd(&out[(size_t)d_ * CC + c], scores[(size_t)s_ * CC + c] * a);
}

extern "C" void kernel_launch(void* const* d_in, const int* in_sizes, int n_in,
                              void* d_out, int out_size, void* d_ws, size_t ws_size,
                              hipStream_t stream) {
    const float* embedding = (const float*)d_in[0];
    const float* scores    = (const float*)d_in[1];
    const int*   src       = (const int*)d_in[2];
    const int*   dst       = (const int*)d_in[3];
    const int*   typ       = (const int*)d_in[4];
    const float* W1  = (const float*)d_in[5];
    const float* b1  = (const float*)d_in[6];
    const float* W2  = (const float*)d_in[7];
    const float* b2  = (const float*)d_in[8];
    const float* ln_g = (const float*)d_in[9];
    const float* ln_b = (const float*)d_in[10];
    const float* Wl  = (const float*)d_in[11];
    const float* bl  = (const float*)d_in[12];
    const float* Wr  = (const float*)d_in[13];
    const float* br  = (const float*)d_in[14];
    const float* We  = (const float*)d_in[15];
    const float* be  = (const float*)d_in[16];
    const float* emb_table = (const float*)d_in[17];
    float* out = (float*)d_out;
    (void)in_sizes; (void)n_in; (void)out_size; (void)ws_size;

    // workspace layout (floats)
    float* ws   = (float*)d_ws;
    float* h    = ws;                      // N*H
    float* q    = h  + (size_t)NN * HH;    // N*H
    float* k1   = q  + (size_t)NN * HH;    // N*H
    float* k2t  = k1 + (size_t)NN * HH;    // 1024 (ET*H padded)
    float* alp  = k2t + 1024;              // E
    float* mbuf = alp + EE;                // N
    float* sbuf = mbuf + NN;               // N
    float* Gch  = sbuf + NN;               // CH * 4H

    hipMemsetAsync(out,  0, (size_t)NN * CC * sizeof(float), stream);
    hipMemsetAsync(sbuf, 0, (size_t)NN * sizeof(float), stream);
    init_m_kernel<<<(NN + 255) / 256, 256, 0, stream>>>(mbuf);
    k2_kernel<<<ETT, HH, 0, stream>>>(emb_table, We, be, k2t);

    // MLP: h = LN(gelu(X@W1+b1)@W2+b2), chunked over rows
    for (int r0 = 0; r0 < NN; r0 += CH) {
        int mr = (NN - r0 < CH) ? (NN - r0) : CH;
        dim3 g1(4 * HH / 64, (mr + 63) / 64);
        gemm_bias_act<true><<<g1, 256, 0, stream>>>(
            embedding + (size_t)r0 * HH, W1, b1, Gch, mr, HH, 4 * HH);
        dim3 g2(HH / 64, (mr + 63) / 64);
        gemm_bias_act<false><<<g2, 256, 0, stream>>>(
            Gch, W2, b2, h + (size_t)r0 * HH, mr, 4 * HH, HH);
    }
    ln_kernel<<<NN, HH, 0, stream>>>(h, ln_g, ln_b);

    dim3 gq(HH / 64, (NN + 63) / 64);
    gemm_bias_act<false><<<gq, 256, 0, stream>>>(h, Wl, bl, q,  NN, HH, HH);
    gemm_bias_act<false><<<gq, 256, 0, stream>>>(h, Wr, br, k1, NN, HH, HH);

    edge_alpha_kernel<<<(EE + 15) / 16, 256, 0, stream>>>(q, k1, k2t, src, dst, typ, alp, mbuf);
    edge_exp_kernel<<<(EE + 255) / 256, 256, 0, stream>>>(alp, dst, mbuf, sbuf);
    edge_scatter_kernel<<<(EE + 3) / 4, 256, 0, stream>>>(alp, src, dst, sbuf, scores, out);
}

// Round 2
// 768.434 us; speedup vs baseline: 2.1495x; 2.1495x over previous
//
#include <hip/hip_runtime.h>
#include <math.h>

#define NN 50000
#define EE 800000
#define HH 256
#define CC 64
#define ETT 3
#define EFF 20
#define NPAD 50048          // NN rounded to 128
#define CHROWS 12544        // GEMM row chunk (multiple of 128)

typedef __bf16 bf16x8 __attribute__((ext_vector_type(8)));
typedef float f32x4 __attribute__((ext_vector_type(4)));

__device__ __forceinline__ float gelu_f(float x) {
    const float k0 = 0.7978845608028654f; // sqrt(2/pi)
    float x3 = x * x * x;
    return 0.5f * x * (1.0f + tanhf(k0 * (x + 0.044715f * x3)));
}

__device__ __forceinline__ unsigned short f2bf(float x) {
    unsigned int u = __float_as_uint(x);
    u = (u + 0x7FFFu + ((u >> 16) & 1u)) >> 16;
    return (unsigned short)u;
}

__device__ __forceinline__ void gld_lds16(const void* g, void* l) {
    __builtin_amdgcn_global_load_lds(
        (const __attribute__((address_space(1))) unsigned int*)g,
        (__attribute__((address_space(3))) unsigned int*)l,
        16, 0, 0);
}

// ---------------------------------------------------------------------------
// C[M,Nc] = act(A_bf16[M,K] @ BT_bf16[Nc,K]^T + bias)
// 128x128 tile, BK=64, 4 waves, 16x16x32 bf16 MFMA, global_load_lds staging,
// XOR-swizzled LDS (chunk ^= row&7) so ds_read_b128 frags are ~conflict-free.
// A rows [row0, row0+gridDim.y*128) must be readable (pad allocation);
// C writes guarded by row<M. K%64==0, Nc%128==0.
// ---------------------------------------------------------------------------
template<bool GELU, bool OUT_BF16>
__global__ __launch_bounds__(256) void mfma_gemm(
    const unsigned short* __restrict__ A,
    const unsigned short* __restrict__ BT,
    const float* __restrict__ bias,
    void* __restrict__ C,
    int M, int K, int Nc)
{
    __shared__ __align__(16) unsigned char lds[32768]; // A: [0,16K), B: [16K,32K)
    const int t    = threadIdx.x;
    const int lane = t & 63;
    const int wv   = t >> 6;
    const int wr   = wv >> 1, wc = wv & 1;
    const int row0 = blockIdx.y * 128;
    const int col0 = blockIdx.x * 128;

    f32x4 acc[4][4] = {};

    // staging decomposition: issue i covers rows [i*32, i*32+32), thread t ->
    // LDS linear byte i*4096 + t*16  == (row = i*32 + t/8, slot = t%8)
    const int srow  = t >> 3;            // 0..31
    const int sslot = t & 7;
    const int schunk = sslot ^ (srow & 7);  // global k-chunk stored at this slot

    const unsigned short* Ab = A  + (size_t)row0 * K;
    const unsigned short* Bb = BT + (size_t)col0 * K;

    for (int k0 = 0; k0 < K; k0 += 64) {
        #pragma unroll
        for (int i = 0; i < 4; ++i)
            gld_lds16(Ab + (size_t)(i * 32 + srow) * K + k0 + schunk * 8,
                      &lds[i * 4096 + t * 16]);
        #pragma unroll
        for (int i = 0; i < 4; ++i)
            gld_lds16(Bb + (size_t)(i * 32 + srow) * K + k0 + schunk * 8,
                      &lds[16384 + i * 4096 + t * 16]);
        __syncthreads();

        #pragma unroll
        for (int kk = 0; kk < 2; ++kk) {
            bf16x8 af[4], bf[4];
            #pragma unroll
            for (int m = 0; m < 4; ++m) {
                int r  = wr * 64 + m * 16 + (lane & 15);
                int ch = (kk * 4 + (lane >> 4)) ^ (r & 7);
                af[m] = *reinterpret_cast<const bf16x8*>(&lds[r * 128 + ch * 16]);
            }
            #pragma unroll
            for (int n = 0; n < 4; ++n) {
                int r  = wc * 64 + n * 16 + (lane & 15);
                int ch = (kk * 4 + (lane >> 4)) ^ (r & 7);
                bf[n] = *reinterpret_cast<const bf16x8*>(&lds[16384 + r * 128 + ch * 16]);
            }
            #pragma unroll
            for (int m = 0; m < 4; ++m)
                #pragma unroll
                for (int n = 0; n < 4; ++n)
                    acc[m][n] = __builtin_amdgcn_mfma_f32_16x16x32_bf16(
                        af[m], bf[n], acc[m][n], 0, 0, 0);
        }
        __syncthreads();
    }

    // epilogue: C/D layout col=lane&15, row=(lane>>4)*4+reg
    #pragma unroll
    for (int n = 0; n < 4; ++n) {
        int col = col0 + wc * 64 + n * 16 + (lane & 15);
        float bv = bias[col];
        #pragma unroll
        for (int m = 0; m < 4; ++m) {
            #pragma unroll
            for (int rg = 0; rg < 4; ++rg) {
                int row = row0 + wr * 64 + m * 16 + (lane >> 4) * 4 + rg;
                if (row < M) {
                    float v = acc[m][n][rg] + bv;
                    if (GELU) v = gelu_f(v);
                    if (OUT_BF16)
                        ((unsigned short*)C)[(size_t)row * Nc + col] = f2bf(v);
                    else
                        ((float*)C)[(size_t)row * Nc + col] = v;
                }
            }
        }
    }
}

// LayerNorm over rows of h [N,256] fp32 -> hb bf16. One 256-thr block per row.
__global__ __launch_bounds__(256) void ln_kernel(
    const float* __restrict__ h, const float* __restrict__ g,
    const float* __restrict__ b, unsigned short* __restrict__ hb)
{
    int row = blockIdx.x;
    int t = threadIdx.x;
    float x = h[(size_t)row * HH + t];
    float s1 = x, s2 = x * x;
    #pragma unroll
    for (int off = 32; off; off >>= 1) {
        s1 += __shfl_down(s1, off);
        s2 += __shfl_down(s2, off);
    }
    __shared__ float r1[4], r2[4];
    int wid = t >> 6;
    if ((t & 63) == 0) { r1[wid] = s1; r2[wid] = s2; }
    __syncthreads();
    if (t == 0) {
        float a = 0.f, bb = 0.f;
        #pragma unroll
        for (int i = 0; i < 4; ++i) { a += r1[i]; bb += r2[i]; }
        r1[0] = a; r2[0] = bb;
    }
    __syncthreads();
    float mean = r1[0] * (1.0f / HH);
    float var  = r2[0] * (1.0f / HH) - mean * mean;
    float xn = (x - mean) * rsqrtf(var + 1e-5f);
    hb[(size_t)row * HH + t] = f2bf(xn * g[t] + b[t]);
}

// k2 per edge-type (bf16 out): k2t[t][h] = gelu(emb_table[t]) @ We + be
__global__ void k2_kernel(const float* __restrict__ emb_table,
                          const float* __restrict__ We, const float* __restrict__ be,
                          unsigned short* __restrict__ k2t)
{
    int ty = blockIdx.x;
    int hc = threadIdx.x;
    float acc = be[hc];
    #pragma unroll
    for (int f = 0; f < EFF; ++f)
        acc += gelu_f(emb_table[ty * EFF + f]) * We[f * HH + hc];
    k2t[ty * HH + hc] = f2bf(acc);
}

__global__ void init_m_kernel(float* __restrict__ m) {
    int i = blockIdx.x * 256 + threadIdx.x;
    if (i < NN) m[i] = -INFINITY;
}

// fp32 -> bf16, 4 elems/thread
__global__ void f2bf4_kernel(const float* __restrict__ in,
                             unsigned short* __restrict__ out, int n4)
{
    int i = blockIdx.x * 256 + threadIdx.x;
    if (i >= n4) return;
    float4 v = reinterpret_cast<const float4*>(in)[i];
    ushort4 o;
    o.x = f2bf(v.x); o.y = f2bf(v.y); o.z = f2bf(v.z); o.w = f2bf(v.w);
    reinterpret_cast<ushort4*>(out)[i] = o;
}

// in [R][Cc] fp32 -> out [Cc][R] bf16
__global__ void transpose_f2bf(const float* __restrict__ in,
                               unsigned short* __restrict__ out, int R, int Cc)
{
    int o = blockIdx.x * 256 + threadIdx.x;
    if (o >= R * Cc) return;
    int c = o / R, r = o - c * R;
    out[o] = f2bf(in[r * Cc + c]);
}

// alpha = <q[dst], k1[src]+k2t[type]> / 16; segment-max into m. 16 lanes/edge.
__global__ __launch_bounds__(256) void edge_alpha_kernel(
    const unsigned short* __restrict__ q, const unsigned short* __restrict__ k1,
    const unsigned short* __restrict__ k2t, const int* __restrict__ src,
    const int* __restrict__ dst, const int* __restrict__ typ,
    float* __restrict__ alpha, float* __restrict__ m)
{
    int t = threadIdx.x;
    int e = blockIdx.x * 16 + (t >> 4);
    int lane = t & 15;
    if (e >= EE) return;
    int s_ = src[e], d_ = dst[e], ty_ = typ[e];
    const uint4* qp = reinterpret_cast<const uint4*>(q  + (size_t)d_ * HH);
    const uint4* kp = reinterpret_cast<const uint4*>(k1 + (size_t)s_ * HH);
    const uint4* ep = reinterpret_cast<const uint4*>(k2t + ty_ * HH);
    float acc = 0.f;
    #pragma unroll
    for (int i = 0; i < 2; ++i) {
        uint4 qv = qp[lane * 2 + i], kv = kp[lane * 2 + i], ev = ep[lane * 2 + i];
        const unsigned int* qu = (const unsigned int*)&qv;
        const unsigned int* ku = (const unsigned int*)&kv;
        const unsigned int* eu = (const unsigned int*)&ev;
        #pragma unroll
        for (int w = 0; w < 4; ++w) {
            float ql = __uint_as_float(qu[w] << 16);
            float qh = __uint_as_float(qu[w] & 0xFFFF0000u);
            float kl = __uint_as_float(ku[w] << 16);
            float kh = __uint_as_float(ku[w] & 0xFFFF0000u);
            float el = __uint_as_float(eu[w] << 16);
            float eh = __uint_as_float(eu[w] & 0xFFFF0000u);
            acc += ql * (kl + el) + qh * (kh + eh);
        }
    }
    acc += __shfl_xor(acc, 8);
    acc += __shfl_xor(acc, 4);
    acc += __shfl_xor(acc, 2);
    acc += __shfl_xor(acc, 1);
    if (lane == 0) {
        float a = acc * 0.0625f;   // 1/sqrt(256)
        alpha[e] = a;
        if (a >= 0.f) atomicMax((int*)&m[d_], __float_as_int(a));
        else          atomicMin((unsigned int*)&m[d_], __float_as_uint(a));
    }
}

__global__ void edge_exp_kernel(float* __restrict__ alpha, const int* __restrict__ dst,
                                const float* __restrict__ m, float* __restrict__ s)
{
    int e = blockIdx.x * 256 + threadIdx.x;
    if (e >= EE) return;
    int d_ = dst[e];
    float ex = expf(alpha[e] - m[d_]);
    alpha[e] = ex;
    atomicAdd(&s[d_], ex);
}

__global__ __launch_bounds__(256) void edge_scatter_kernel(
    const float* __restrict__ alpha, const int* __restrict__ src,
    const int* __restrict__ dst, const float* __restrict__ s,
    const float* __restrict__ scores, float* __restrict__ out)
{
    int t = threadIdx.x;
    int e = blockIdx.x * 4 + (t >> 6);
    int c = t & 63;
    if (e >= EE) return;
    int s_ = src[e], d_ = dst[e];
    float a = alpha[e] / s[d_];
    atomicAdd(&out[(size_t)d_ * CC + c], scores[(size_t)s_ * CC + c] * a);
}

extern "C" void kernel_launch(void* const* d_in, const int* in_sizes, int n_in,
                              void* d_out, int out_size, void* d_ws, size_t ws_size,
                              hipStream_t stream) {
    const float* embedding = (const float*)d_in[0];
    const float* scores    = (const float*)d_in[1];
    const int*   src       = (const int*)d_in[2];
    const int*   dst       = (const int*)d_in[3];
    const int*   typ       = (const int*)d_in[4];
    const float* W1  = (const float*)d_in[5];
    const float* b1  = (const float*)d_in[6];
    const float* W2  = (const float*)d_in[7];
    const float* b2  = (const float*)d_in[8];
    const float* ln_g = (const float*)d_in[9];
    const float* ln_b = (const float*)d_in[10];
    const float* Wl  = (const float*)d_in[11];
    const float* bl  = (const float*)d_in[12];
    const float* Wr  = (const float*)d_in[13];
    const float* br  = (const float*)d_in[14];
    const float* We  = (const float*)d_in[15];
    const float* be  = (const float*)d_in[16];
    const float* emb_table = (const float*)d_in[17];
    float* out = (float*)d_out;
    (void)in_sizes; (void)n_in; (void)out_size; (void)ws_size;

    // ---- workspace carve-up (bytes, 256-aligned chunks) ----
    char* w = (char*)d_ws;
    auto take = [&](size_t bytes) {
        char* p = w;
        w += (bytes + 255) & ~(size_t)255;
        return p;
    };
    unsigned short* embA = (unsigned short*)take((size_t)NPAD * HH * 2);
    unsigned short* hb   = (unsigned short*)take((size_t)NPAD * HH * 2);
    unsigned short* qb   = (unsigned short*)take((size_t)NPAD * HH * 2);
    unsigned short* k1b  = (unsigned short*)take((size_t)NPAD * HH * 2);
    float*          h    = (float*)take((size_t)NN * HH * 4);
    unsigned short* Gch  = (unsigned short*)take((size_t)CHROWS * 4 * HH * 2);
    unsigned short* W1T  = (unsigned short*)take((size_t)4 * HH * HH * 2);
    unsigned short* W2T  = (unsigned short*)take((size_t)HH * 4 * HH * 2);
    unsigned short* WlT  = (unsigned short*)take((size_t)HH * HH * 2);
    unsigned short* WrT  = (unsigned short*)take((size_t)HH * HH * 2);
    unsigned short* k2t  = (unsigned short*)take(2048);
    float*          alp  = (float*)take((size_t)EE * 4);
    float*          mbuf = (float*)take((size_t)NN * 4);
    float*          sbuf = (float*)take((size_t)NN * 4);

    hipMemsetAsync(out,  0, (size_t)NN * CC * sizeof(float), stream);
    hipMemsetAsync(sbuf, 0, (size_t)NN * sizeof(float), stream);
    init_m_kernel<<<(NN + 255) / 256, 256, 0, stream>>>(mbuf);
    k2_kernel<<<ETT, HH, 0, stream>>>(emb_table, We, be, k2t);

    // input conversions
    f2bf4_kernel<<<(NN * HH / 4 + 255) / 256, 256, 0, stream>>>(embedding, embA, NN * HH / 4);
    transpose_f2bf<<<(HH * 4 * HH + 255) / 256, 256, 0, stream>>>(W1, W1T, HH, 4 * HH);
    transpose_f2bf<<<(HH * 4 * HH + 255) / 256, 256, 0, stream>>>(W2, W2T, 4 * HH, HH);
    transpose_f2bf<<<(HH * HH + 255) / 256, 256, 0, stream>>>(Wl, WlT, HH, HH);
    transpose_f2bf<<<(HH * HH + 255) / 256, 256, 0, stream>>>(Wr, WrT, HH, HH);

    // MLP: h = gelu(X@W1+b1)@W2+b2 (chunked), then LN -> hb (bf16)
    for (int r0 = 0; r0 < NN; r0 += CHROWS) {
        int mr = (NN - r0 < CHROWS) ? (NN - r0) : CHROWS;
        int gy = (mr + 127) / 128;
        dim3 g1(4 * HH / 128, gy);
        mfma_gemm<true, true><<<g1, 256, 0, stream>>>(
            embA + (size_t)r0 * HH, W1T, b1, Gch, mr, HH, 4 * HH);
        dim3 g2(HH / 128, gy);
        mfma_gemm<false, false><<<g2, 256, 0, stream>>>(
            Gch, W2T, b2, h + (size_t)r0 * HH, mr, 4 * HH, HH);
    }
    ln_kernel<<<NN, HH, 0, stream>>>(h, ln_g, ln_b, hb);

    dim3 gq(HH / 128, (NN + 127) / 128);
    mfma_gemm<false, true><<<gq, 256, 0, stream>>>(hb, WlT, bl, qb,  NN, HH, HH);
    mfma_gemm<false, true><<<gq, 256, 0, stream>>>(hb, WrT, br, k1b, NN, HH, HH);

    edge_alpha_kernel<<<(EE + 15) / 16, 256, 0, stream>>>(qb, k1b, k2t, src, dst, typ, alp, mbuf);
    edge_exp_kernel<<<(EE + 255) / 256, 256, 0, stream>>>(alp, dst, mbuf, sbuf);
    edge_scatter_kernel<<<(EE + 3) / 4, 256, 0, stream>>>(alp, src, dst, sbuf, scores, out);
}

// Round 3
// 752.576 us; speedup vs baseline: 2.1948x; 1.0211x over previous
//
#include <hip/hip_runtime.h>
#include <math.h>

#define NN 50000
#define EE 800000
#define HH 256
#define CC 64
#define ETT 3
#define EFF 20
#define NPAD 50048          // NN rounded to 128
#define CHROWS 12544        // GEMM row chunk (multiple of 128)

typedef __bf16 bf16x8 __attribute__((ext_vector_type(8)));
typedef float f32x4 __attribute__((ext_vector_type(4)));

__device__ __forceinline__ float gelu_f(float x) {
    const float k0 = 0.7978845608028654f; // sqrt(2/pi)
    float x3 = x * x * x;
    return 0.5f * x * (1.0f + tanhf(k0 * (x + 0.044715f * x3)));
}

__device__ __forceinline__ unsigned short f2bf(float x) {
    unsigned int u = __float_as_uint(x);
    u = (u + 0x7FFFu + ((u >> 16) & 1u)) >> 16;
    return (unsigned short)u;
}

__device__ __forceinline__ float bf2f(unsigned short x) {
    return __uint_as_float((unsigned int)x << 16);
}

__device__ __forceinline__ void gld_lds16(const void* g, void* l) {
    __builtin_amdgcn_global_load_lds(
        (const __attribute__((address_space(1))) unsigned int*)g,
        (__attribute__((address_space(3))) unsigned int*)l,
        16, 0, 0);
}

// ---------------------------------------------------------------------------
// C[M,Nc] = act(A_bf16[M,K] @ BT_bf16[Nc,K]^T + bias); 128x128 tile, BK=64,
// 4 waves, 16x16x32 bf16 MFMA, global_load_lds, XOR-swizzled LDS.
// ---------------------------------------------------------------------------
template<bool GELU, bool OUT_BF16>
__global__ __launch_bounds__(256) void mfma_gemm(
    const unsigned short* __restrict__ A,
    const unsigned short* __restrict__ BT,
    const float* __restrict__ bias,
    void* __restrict__ C,
    int M, int K, int Nc)
{
    __shared__ __align__(16) unsigned char lds[32768]; // A: [0,16K), B: [16K,32K)
    const int t    = threadIdx.x;
    const int lane = t & 63;
    const int wv   = t >> 6;
    const int wr   = wv >> 1, wc = wv & 1;
    const int row0 = blockIdx.y * 128;
    const int col0 = blockIdx.x * 128;

    f32x4 acc[4][4] = {};

    const int srow  = t >> 3;               // 0..31
    const int sslot = t & 7;
    const int schunk = sslot ^ (srow & 7);  // global k-chunk stored at this slot

    const unsigned short* Ab = A  + (size_t)row0 * K;
    const unsigned short* Bb = BT + (size_t)col0 * K;

    for (int k0 = 0; k0 < K; k0 += 64) {
        #pragma unroll
        for (int i = 0; i < 4; ++i)
            gld_lds16(Ab + (size_t)(i * 32 + srow) * K + k0 + schunk * 8,
                      &lds[i * 4096 + t * 16]);
        #pragma unroll
        for (int i = 0; i < 4; ++i)
            gld_lds16(Bb + (size_t)(i * 32 + srow) * K + k0 + schunk * 8,
                      &lds[16384 + i * 4096 + t * 16]);
        __syncthreads();

        #pragma unroll
        for (int kk = 0; kk < 2; ++kk) {
            bf16x8 af[4], bf[4];
            #pragma unroll
            for (int m = 0; m < 4; ++m) {
                int r  = wr * 64 + m * 16 + (lane & 15);
                int ch = (kk * 4 + (lane >> 4)) ^ (r & 7);
                af[m] = *reinterpret_cast<const bf16x8*>(&lds[r * 128 + ch * 16]);
            }
            #pragma unroll
            for (int n = 0; n < 4; ++n) {
                int r  = wc * 64 + n * 16 + (lane & 15);
                int ch = (kk * 4 + (lane >> 4)) ^ (r & 7);
                bf[n] = *reinterpret_cast<const bf16x8*>(&lds[16384 + r * 128 + ch * 16]);
            }
            #pragma unroll
            for (int m = 0; m < 4; ++m)
                #pragma unroll
                for (int n = 0; n < 4; ++n)
                    acc[m][n] = __builtin_amdgcn_mfma_f32_16x16x32_bf16(
                        af[m], bf[n], acc[m][n], 0, 0, 0);
        }
        __syncthreads();
    }

    #pragma unroll
    for (int n = 0; n < 4; ++n) {
        int col = col0 + wc * 64 + n * 16 + (lane & 15);
        float bv = bias[col];
        #pragma unroll
        for (int m = 0; m < 4; ++m) {
            #pragma unroll
            for (int rg = 0; rg < 4; ++rg) {
                int row = row0 + wr * 64 + m * 16 + (lane >> 4) * 4 + rg;
                if (row < M) {
                    float v = acc[m][n][rg] + bv;
                    if (GELU) v = gelu_f(v);
                    if (OUT_BF16)
                        ((unsigned short*)C)[(size_t)row * Nc + col] = f2bf(v);
                    else
                        ((float*)C)[(size_t)row * Nc + col] = v;
                }
            }
        }
    }
}

// LayerNorm over rows of hpre [N,256] bf16 -> hb bf16. One 256-thr block/row.
__global__ __launch_bounds__(256) void ln_kernel(
    const unsigned short* __restrict__ hpre, const float* __restrict__ g,
    const float* __restrict__ b, unsigned short* __restrict__ hb)
{
    int row = blockIdx.x;
    int t = threadIdx.x;
    float x = bf2f(hpre[(size_t)row * HH + t]);
    float s1 = x, s2 = x * x;
    #pragma unroll
    for (int off = 32; off; off >>= 1) {
        s1 += __shfl_down(s1, off);
        s2 += __shfl_down(s2, off);
    }
    __shared__ float r1[4], r2[4];
    int wid = t >> 6;
    if ((t & 63) == 0) { r1[wid] = s1; r2[wid] = s2; }
    __syncthreads();
    if (t == 0) {
        float a = 0.f, bb = 0.f;
        #pragma unroll
        for (int i = 0; i < 4; ++i) { a += r1[i]; bb += r2[i]; }
        r1[0] = a; r2[0] = bb;
    }
    __syncthreads();
    float mean = r1[0] * (1.0f / HH);
    float var  = r2[0] * (1.0f / HH) - mean * mean;
    float xn = (x - mean) * rsqrtf(var + 1e-5f);
    hb[(size_t)row * HH + t] = f2bf(xn * g[t] + b[t]);
}

// k2 per edge-type (bf16 out): k2t[t][h] = gelu(emb_table[t]) @ We + be
__global__ void k2_kernel(const float* __restrict__ emb_table,
                          const float* __restrict__ We, const float* __restrict__ be,
                          unsigned short* __restrict__ k2t)
{
    int ty = blockIdx.x;
    int hc = threadIdx.x;
    float acc = be[hc];
    #pragma unroll
    for (int f = 0; f < EFF; ++f)
        acc += gelu_f(emb_table[ty * EFF + f]) * We[f * HH + hc];
    k2t[ty * HH + hc] = f2bf(acc);
}

// fp32 -> bf16, 4 elems/thread
__global__ void f2bf4_kernel(const float* __restrict__ in,
                             unsigned short* __restrict__ out, int n4)
{
    int i = blockIdx.x * 256 + threadIdx.x;
    if (i >= n4) return;
    float4 v = reinterpret_cast<const float4*>(in)[i];
    ushort4 o;
    o.x = f2bf(v.x); o.y = f2bf(v.y); o.z = f2bf(v.z); o.w = f2bf(v.w);
    reinterpret_cast<ushort4*>(out)[i] = o;
}

// in [R][Cc] fp32 -> out [Cc][R] bf16
__global__ void transpose_f2bf(const float* __restrict__ in,
                               unsigned short* __restrict__ out, int R, int Cc)
{
    int o = blockIdx.x * 256 + threadIdx.x;
    if (o >= R * Cc) return;
    int c = o / R, r = o - c * R;
    out[o] = f2bf(in[r * Cc + c]);
}

__global__ void concat_bias(const float* __restrict__ a, const float* __restrict__ b,
                            float* __restrict__ o)
{
    int t = threadIdx.x;
    o[t] = (t < HH) ? a[t] : b[t - HH];
}

// ---- CSR build ----
__global__ void hist_kernel(const int* __restrict__ dst, int* __restrict__ cnt)
{
    int e = blockIdx.x * 256 + threadIdx.x;
    if (e < EE) atomicAdd(&cnt[dst[e]], 1);
}

__global__ __launch_bounds__(1024) void scan_kernel(
    const int* __restrict__ cnt, int* __restrict__ off, int* __restrict__ cur)
{
    __shared__ int part[1024];
    const int t = threadIdx.x;
    const int per = (NN + 1023) / 1024;     // 49
    const int base = t * per;
    int sum = 0;
    for (int i = 0; i < per; ++i) {
        int idx = base + i;
        if (idx < NN) sum += cnt[idx];
    }
    part[t] = sum;
    __syncthreads();
    for (int d = 1; d < 1024; d <<= 1) {
        int v = (t >= d) ? part[t - d] : 0;
        __syncthreads();
        part[t] += v;
        __syncthreads();
    }
    int run = part[t] - sum;                // exclusive prefix of this chunk
    for (int i = 0; i < per; ++i) {
        int idx = base + i;
        if (idx < NN) {
            off[idx] = run;
            cur[idx] = run;
            run += cnt[idx];
        }
    }
    if (t == 1023) off[NN] = run;           // == EE
}

__global__ void fill_kernel(const int* __restrict__ src, const int* __restrict__ dst,
                            const int* __restrict__ typ, int* __restrict__ cur,
                            unsigned int* __restrict__ pack)
{
    int e = blockIdx.x * 256 + threadIdx.x;
    if (e >= EE) return;
    int pos = atomicAdd(&cur[dst[e]], 1);
    pack[pos] = (unsigned int)src[e] | ((unsigned int)typ[e] << 24);
}

// ---- fused per-dst attention: one wave per node, online softmax ----
__global__ __launch_bounds__(256) void fused_edge_kernel(
    const unsigned short* __restrict__ qk,   // [NPAD][512] bf16: [q | k1]
    const unsigned short* __restrict__ k2t,  // [ET][256] bf16
    const int* __restrict__ off, const unsigned int* __restrict__ pack,
    const float* __restrict__ scores, float* __restrict__ out)
{
    const int t = threadIdx.x;
    const int lane = t & 63;
    const int d = blockIdx.x * 4 + (t >> 6);
    if (d >= NN) return;

    // q[d] slice: 4 bf16 per lane
    uint2 qv = *reinterpret_cast<const uint2*>(qk + (size_t)d * 512 + lane * 4);
    float q0 = bf2f((unsigned short)(qv.x & 0xFFFF));
    float q1 = bf2f((unsigned short)(qv.x >> 16));
    float q2 = bf2f((unsigned short)(qv.y & 0xFFFF));
    float q3 = bf2f((unsigned short)(qv.y >> 16));

    // k2t in registers (static names; runtime-ty selected via cndmask)
    float e00, e01, e02, e03, e10, e11, e12, e13, e20, e21, e22, e23;
    {
        uint2 v0 = *reinterpret_cast<const uint2*>(k2t + 0 * HH + lane * 4);
        uint2 v1 = *reinterpret_cast<const uint2*>(k2t + 1 * HH + lane * 4);
        uint2 v2 = *reinterpret_cast<const uint2*>(k2t + 2 * HH + lane * 4);
        e00 = bf2f((unsigned short)(v0.x & 0xFFFF)); e01 = bf2f((unsigned short)(v0.x >> 16));
        e02 = bf2f((unsigned short)(v0.y & 0xFFFF)); e03 = bf2f((unsigned short)(v0.y >> 16));
        e10 = bf2f((unsigned short)(v1.x & 0xFFFF)); e11 = bf2f((unsigned short)(v1.x >> 16));
        e12 = bf2f((unsigned short)(v1.y & 0xFFFF)); e13 = bf2f((unsigned short)(v1.y >> 16));
        e20 = bf2f((unsigned short)(v2.x & 0xFFFF)); e21 = bf2f((unsigned short)(v2.x >> 16));
        e22 = bf2f((unsigned short)(v2.y & 0xFFFF)); e23 = bf2f((unsigned short)(v2.y >> 16));
    }

    const int beg = off[d], end = off[d + 1];
    float m = -INFINITY, s = 0.f, acc = 0.f;

    for (int i = beg; i < end; ++i) {
        unsigned int pk = pack[i];
        int sr = pk & 0xFFFFFF;
        int ty = pk >> 24;

        uint2 kv = *reinterpret_cast<const uint2*>(qk + (size_t)sr * 512 + 256 + lane * 4);
        float k0 = bf2f((unsigned short)(kv.x & 0xFFFF));
        float k1 = bf2f((unsigned short)(kv.x >> 16));
        float k2 = bf2f((unsigned short)(kv.y & 0xFFFF));
        float k3 = bf2f((unsigned short)(kv.y >> 16));

        float f0 = (ty == 0) ? e00 : (ty == 1) ? e10 : e20;
        float f1 = (ty == 0) ? e01 : (ty == 1) ? e11 : e21;
        float f2 = (ty == 0) ? e02 : (ty == 1) ? e12 : e22;
        float f3 = (ty == 0) ? e03 : (ty == 1) ? e13 : e23;

        float p = q0 * (k0 + f0) + q1 * (k1 + f1) + q2 * (k2 + f2) + q3 * (k3 + f3);
        p += __shfl_xor(p, 1);
        p += __shfl_xor(p, 2);
        p += __shfl_xor(p, 4);
        p += __shfl_xor(p, 8);
        p += __shfl_xor(p, 16);
        p += __shfl_xor(p, 32);
        float a = p * 0.0625f;               // 1/sqrt(256)

        float sc = scores[(size_t)sr * CC + lane];
        if (a > m) {                          // wave-uniform branch
            float c_ = __expf(m - a);         // exp(-inf)=0 on first edge
            s = s * c_ + 1.f;
            acc = acc * c_ + sc;
            m = a;
        } else {
            float w = __expf(a - m);
            s += w;
            acc += w * sc;
        }
    }
    out[(size_t)d * CC + lane] = (end > beg) ? acc / s : 0.f;
}

extern "C" void kernel_launch(void* const* d_in, const int* in_sizes, int n_in,
                              void* d_out, int out_size, void* d_ws, size_t ws_size,
                              hipStream_t stream) {
    const float* embedding = (const float*)d_in[0];
    const float* scores    = (const float*)d_in[1];
    const int*   src       = (const int*)d_in[2];
    const int*   dst       = (const int*)d_in[3];
    const int*   typ       = (const int*)d_in[4];
    const float* W1  = (const float*)d_in[5];
    const float* b1  = (const float*)d_in[6];
    const float* W2  = (const float*)d_in[7];
    const float* b2  = (const float*)d_in[8];
    const float* ln_g = (const float*)d_in[9];
    const float* ln_b = (const float*)d_in[10];
    const float* Wl  = (const float*)d_in[11];
    const float* bl  = (const float*)d_in[12];
    const float* Wr  = (const float*)d_in[13];
    const float* br  = (const float*)d_in[14];
    const float* We  = (const float*)d_in[15];
    const float* be  = (const float*)d_in[16];
    const float* emb_table = (const float*)d_in[17];
    float* out = (float*)d_out;
    (void)in_sizes; (void)n_in; (void)out_size; (void)ws_size;

    // ---- workspace carve-up ----
    char* w = (char*)d_ws;
    auto take = [&](size_t bytes) {
        char* p = w;
        w += (bytes + 255) & ~(size_t)255;
        return p;
    };
    unsigned short* embA = (unsigned short*)take((size_t)NPAD * HH * 2);
    unsigned short* hpre = (unsigned short*)take((size_t)NN * HH * 2);
    unsigned short* hb   = (unsigned short*)take((size_t)NPAD * HH * 2);
    unsigned short* qk   = (unsigned short*)take((size_t)NPAD * 512 * 2);
    unsigned short* Gch  = (unsigned short*)take((size_t)CHROWS * 4 * HH * 2);
    unsigned short* W1T  = (unsigned short*)take((size_t)4 * HH * HH * 2);
    unsigned short* W2T  = (unsigned short*)take((size_t)HH * 4 * HH * 2);
    unsigned short* WlrT = (unsigned short*)take((size_t)512 * HH * 2);
    unsigned short* k2t  = (unsigned short*)take(2048);
    float*          blr  = (float*)take(512 * 4);
    int*            cnt  = (int*)take((size_t)NN * 4);
    int*            offb = (int*)take((size_t)(NN + 1) * 4);
    int*            cur  = (int*)take((size_t)NN * 4);
    unsigned int*   pack = (unsigned int*)take((size_t)EE * 4);

    // ---- CSR build (independent of GEMMs) ----
    hipMemsetAsync(cnt, 0, (size_t)NN * 4, stream);
    hist_kernel<<<(EE + 255) / 256, 256, 0, stream>>>(dst, cnt);
    scan_kernel<<<1, 1024, 0, stream>>>(cnt, offb, cur);
    fill_kernel<<<(EE + 255) / 256, 256, 0, stream>>>(src, dst, typ, cur, pack);

    // ---- small prep ----
    k2_kernel<<<ETT, HH, 0, stream>>>(emb_table, We, be, k2t);
    concat_bias<<<1, 512, 0, stream>>>(bl, br, blr);
    f2bf4_kernel<<<(NN * HH / 4 + 255) / 256, 256, 0, stream>>>(embedding, embA, NN * HH / 4);
    transpose_f2bf<<<(HH * 4 * HH + 255) / 256, 256, 0, stream>>>(W1, W1T, HH, 4 * HH);
    transpose_f2bf<<<(HH * 4 * HH + 255) / 256, 256, 0, stream>>>(W2, W2T, 4 * HH, HH);
    transpose_f2bf<<<(HH * HH + 255) / 256, 256, 0, stream>>>(Wl, WlrT, HH, HH);
    transpose_f2bf<<<(HH * HH + 255) / 256, 256, 0, stream>>>(Wr, WlrT + HH * HH, HH, HH);

    // ---- MLP: hpre = gelu(X@W1+b1)@W2+b2 (bf16), then LN -> hb ----
    for (int r0 = 0; r0 < NN; r0 += CHROWS) {
        int mr = (NN - r0 < CHROWS) ? (NN - r0) : CHROWS;
        int gy = (mr + 127) / 128;
        dim3 g1(4 * HH / 128, gy);
        mfma_gemm<true, true><<<g1, 256, 0, stream>>>(
            embA + (size_t)r0 * HH, W1T, b1, Gch, mr, HH, 4 * HH);
        dim3 g2(HH / 128, gy);
        mfma_gemm<false, true><<<g2, 256, 0, stream>>>(
            Gch, W2T, b2, hpre + (size_t)r0 * HH, mr, 4 * HH, HH);
    }
    ln_kernel<<<NN, HH, 0, stream>>>(hpre, ln_g, ln_b, hb);

    // ---- q|k1 projection in one GEMM (Nc=512) ----
    dim3 gq(512 / 128, (NN + 127) / 128);
    mfma_gemm<false, true><<<gq, 256, 0, stream>>>(hb, WlrT, blr, qk, NN, HH, 512);

    // ---- fused edge phase ----
    fused_edge_kernel<<<(NN + 3) / 4, 256, 0, stream>>>(qk, k2t, offb, pack, scores, out);
}

// Round 4
// 537.089 us; speedup vs baseline: 3.0754x; 1.4012x over previous
//
#include <hip/hip_runtime.h>
#include <math.h>

#define NN 50000
#define EE 800000
#define HH 256
#define CC 64
#define ETT 3
#define EFF 20
#define NPAD 50048          // NN rounded to 128
#define CHROWS 25088        // GEMM row chunk (multiple of 128)
#define NB 196              // scan blocks = ceil(NN/256)

typedef __bf16 bf16x8 __attribute__((ext_vector_type(8)));
typedef float f32x4 __attribute__((ext_vector_type(4)));

__device__ __forceinline__ float gelu_f(float x) {
    const float k0 = 0.7978845608028654f; // sqrt(2/pi)
    float x3 = x * x * x;
    return 0.5f * x * (1.0f + tanhf(k0 * (x + 0.044715f * x3)));
}

__device__ __forceinline__ unsigned short f2bf(float x) {
    unsigned int u = __float_as_uint(x);
    u = (u + 0x7FFFu + ((u >> 16) & 1u)) >> 16;
    return (unsigned short)u;
}

__device__ __forceinline__ float bf2f(unsigned short x) {
    return __uint_as_float((unsigned int)x << 16);
}

__device__ __forceinline__ void gld_lds16(const void* g, void* l) {
    __builtin_amdgcn_global_load_lds(
        (const __attribute__((address_space(1))) unsigned int*)g,
        (__attribute__((address_space(3))) unsigned int*)l,
        16, 0, 0);
}

// ---------------------------------------------------------------------------
// C[M,Nc] = act(A_bf16[M,K] @ BT_bf16[Nc,K]^T + bias); 128x128 tile, BK=64,
// 4 waves, 16x16x32 bf16 MFMA, global_load_lds, XOR-swizzled LDS.
// ---------------------------------------------------------------------------
template<bool GELU, bool OUT_BF16>
__global__ __launch_bounds__(256) void mfma_gemm(
    const unsigned short* __restrict__ A,
    const unsigned short* __restrict__ BT,
    const float* __restrict__ bias,
    void* __restrict__ C,
    int M, int K, int Nc)
{
    __shared__ __align__(16) unsigned char lds[32768]; // A: [0,16K), B: [16K,32K)
    const int t    = threadIdx.x;
    const int lane = t & 63;
    const int wv   = t >> 6;
    const int wr   = wv >> 1, wc = wv & 1;
    const int row0 = blockIdx.y * 128;
    const int col0 = blockIdx.x * 128;

    f32x4 acc[4][4] = {};

    const int srow  = t >> 3;               // 0..31
    const int sslot = t & 7;
    const int schunk = sslot ^ (srow & 7);  // global k-chunk stored at this slot

    const unsigned short* Ab = A  + (size_t)row0 * K;
    const unsigned short* Bb = BT + (size_t)col0 * K;

    for (int k0 = 0; k0 < K; k0 += 64) {
        #pragma unroll
        for (int i = 0; i < 4; ++i)
            gld_lds16(Ab + (size_t)(i * 32 + srow) * K + k0 + schunk * 8,
                      &lds[i * 4096 + t * 16]);
        #pragma unroll
        for (int i = 0; i < 4; ++i)
            gld_lds16(Bb + (size_t)(i * 32 + srow) * K + k0 + schunk * 8,
                      &lds[16384 + i * 4096 + t * 16]);
        __syncthreads();

        #pragma unroll
        for (int kk = 0; kk < 2; ++kk) {
            bf16x8 af[4], bf[4];
            #pragma unroll
            for (int m = 0; m < 4; ++m) {
                int r  = wr * 64 + m * 16 + (lane & 15);
                int ch = (kk * 4 + (lane >> 4)) ^ (r & 7);
                af[m] = *reinterpret_cast<const bf16x8*>(&lds[r * 128 + ch * 16]);
            }
            #pragma unroll
            for (int n = 0; n < 4; ++n) {
                int r  = wc * 64 + n * 16 + (lane & 15);
                int ch = (kk * 4 + (lane >> 4)) ^ (r & 7);
                bf[n] = *reinterpret_cast<const bf16x8*>(&lds[16384 + r * 128 + ch * 16]);
            }
            #pragma unroll
            for (int m = 0; m < 4; ++m)
                #pragma unroll
                for (int n = 0; n < 4; ++n)
                    acc[m][n] = __builtin_amdgcn_mfma_f32_16x16x32_bf16(
                        af[m], bf[n], acc[m][n], 0, 0, 0);
        }
        __syncthreads();
    }

    #pragma unroll
    for (int n = 0; n < 4; ++n) {
        int col = col0 + wc * 64 + n * 16 + (lane & 15);
        float bv = bias[col];
        #pragma unroll
        for (int m = 0; m < 4; ++m) {
            #pragma unroll
            for (int rg = 0; rg < 4; ++rg) {
                int row = row0 + wr * 64 + m * 16 + (lane >> 4) * 4 + rg;
                if (row < M) {
                    float v = acc[m][n][rg] + bv;
                    if (GELU) v = gelu_f(v);
                    if (OUT_BF16)
                        ((unsigned short*)C)[(size_t)row * Nc + col] = f2bf(v);
                    else
                        ((float*)C)[(size_t)row * Nc + col] = v;
                }
            }
        }
    }
}

// LayerNorm in-place over rows of h [N,256] bf16. One 256-thr block per row.
__global__ __launch_bounds__(256) void ln_kernel(
    unsigned short* __restrict__ h, const float* __restrict__ g,
    const float* __restrict__ b)
{
    int row = blockIdx.x;
    int t = threadIdx.x;
    float x = bf2f(h[(size_t)row * HH + t]);
    float s1 = x, s2 = x * x;
    #pragma unroll
    for (int off = 32; off; off >>= 1) {
        s1 += __shfl_down(s1, off);
        s2 += __shfl_down(s2, off);
    }
    __shared__ float r1[4], r2[4];
    int wid = t >> 6;
    if ((t & 63) == 0) { r1[wid] = s1; r2[wid] = s2; }
    __syncthreads();
    if (t == 0) {
        float a = 0.f, bb = 0.f;
        #pragma unroll
        for (int i = 0; i < 4; ++i) { a += r1[i]; bb += r2[i]; }
        r1[0] = a; r2[0] = bb;
    }
    __syncthreads();
    float mean = r1[0] * (1.0f / HH);
    float var  = r2[0] * (1.0f / HH) - mean * mean;
    float xn = (x - mean) * rsqrtf(var + 1e-5f);
    h[(size_t)row * HH + t] = f2bf(xn * g[t] + b[t]);
}

// k2 per edge-type (bf16 out): k2t[t][h] = gelu(emb_table[t]) @ We + be
__global__ void k2_kernel(const float* __restrict__ emb_table,
                          const float* __restrict__ We, const float* __restrict__ be,
                          unsigned short* __restrict__ k2t)
{
    int ty = blockIdx.x;
    int hc = threadIdx.x;
    float acc = be[hc];
    #pragma unroll
    for (int f = 0; f < EFF; ++f)
        acc += gelu_f(emb_table[ty * EFF + f]) * We[f * HH + hc];
    k2t[ty * HH + hc] = f2bf(acc);
}

// fp32 -> bf16, 4 elems/thread
__global__ void f2bf4_kernel(const float* __restrict__ in,
                             unsigned short* __restrict__ out, int n4)
{
    int i = blockIdx.x * 256 + threadIdx.x;
    if (i >= n4) return;
    float4 v = reinterpret_cast<const float4*>(in)[i];
    ushort4 o;
    o.x = f2bf(v.x); o.y = f2bf(v.y); o.z = f2bf(v.z); o.w = f2bf(v.w);
    reinterpret_cast<ushort4*>(out)[i] = o;
}

// all 4 weight transposes in one launch; out index coalesced
__global__ void transpose_all(const float* __restrict__ W1, const float* __restrict__ W2,
                              const float* __restrict__ Wl, const float* __restrict__ Wr,
                              unsigned short* __restrict__ W1T,
                              unsigned short* __restrict__ W2T,
                              unsigned short* __restrict__ WlrT)
{
    int gb = blockIdx.x;
    const float* in; unsigned short* outp; int R, Cc, o;
    if (gb < 1024)      { in = W1; outp = W1T;  R = HH;     Cc = 4 * HH; o = gb * 256 + threadIdx.x; }
    else if (gb < 2048) { in = W2; outp = W2T;  R = 4 * HH; Cc = HH;     o = (gb - 1024) * 256 + threadIdx.x; }
    else if (gb < 2304) { in = Wl; outp = WlrT; R = HH;     Cc = HH;     o = (gb - 2048) * 256 + threadIdx.x; }
    else                { in = Wr; outp = WlrT + HH * HH; R = HH; Cc = HH; o = (gb - 2304) * 256 + threadIdx.x; }
    int c = o / R, r = o - c * R;
    outp[o] = f2bf(in[(size_t)r * Cc + c]);
}

__global__ void concat_bias(const float* __restrict__ a, const float* __restrict__ b,
                            float* __restrict__ o)
{
    int t = threadIdx.x;
    o[t] = (t < HH) ? a[t] : b[t - HH];
}

// ---- CSR build ----
__global__ void hist_kernel(const int* __restrict__ dst, int* __restrict__ cnt)
{
    int e = blockIdx.x * 256 + threadIdx.x;
    if (e < EE) atomicAdd(&cnt[dst[e]], 1);
}

// block-local exclusive scan of cnt -> off, block totals -> bsum
__global__ __launch_bounds__(256) void scan_part(
    const int* __restrict__ cnt, int* __restrict__ off, int* __restrict__ bsum)
{
    int b = blockIdx.x, t = threadIdx.x;
    int idx = b * 256 + t;
    int v = (idx < NN) ? cnt[idx] : 0;
    int inc = v;
    #pragma unroll
    for (int o = 1; o < 64; o <<= 1) {
        int u = __shfl_up(inc, o);
        if ((t & 63) >= o) inc += u;
    }
    __shared__ int wt[4];
    if ((t & 63) == 63) wt[t >> 6] = inc;
    __syncthreads();
    int wo = 0;
    #pragma unroll
    for (int w = 0; w < 4; ++w) if (w < (t >> 6)) wo += wt[w];
    if (idx < NN) off[idx] = wo + inc - v;
    if (t == 255) bsum[b] = wo + inc;
}

// exclusive scan of the NB block sums, in place (single block)
__global__ __launch_bounds__(256) void scan_sums(int* __restrict__ bsum)
{
    int t = threadIdx.x;
    int v = (t < NB) ? bsum[t] : 0;
    int inc = v;
    #pragma unroll
    for (int o = 1; o < 64; o <<= 1) {
        int u = __shfl_up(inc, o);
        if ((t & 63) >= o) inc += u;
    }
    __shared__ int wt[4];
    if ((t & 63) == 63) wt[t >> 6] = inc;
    __syncthreads();
    int wo = 0;
    #pragma unroll
    for (int w = 0; w < 4; ++w) if (w < (t >> 6)) wo += wt[w];
    if (t < NB) bsum[t] = wo + inc - v;
}

__global__ void scan_add(int* __restrict__ off, const int* __restrict__ bsum,
                         int* __restrict__ cur)
{
    int b = blockIdx.x, t = threadIdx.x;
    int idx = b * 256 + t;
    if (idx < NN) {
        int o = off[idx] + bsum[b];
        off[idx] = o;
        cur[idx] = o;
    }
    if (idx == 0) off[NN] = EE;
}

__global__ void fill_kernel(const int* __restrict__ src, const int* __restrict__ dst,
                            const int* __restrict__ typ, int* __restrict__ cur,
                            unsigned int* __restrict__ pack)
{
    int e = blockIdx.x * 256 + threadIdx.x;
    if (e >= EE) return;
    int pos = atomicAdd(&cur[dst[e]], 1);
    pack[pos] = (unsigned int)src[e] | ((unsigned int)typ[e] << 24);
}

// ---- fused per-dst attention: one wave per node, online softmax,
//      software-pipelined gathers, branchless update ----
__global__ __launch_bounds__(256) void fused_edge_kernel(
    const unsigned short* __restrict__ qk,   // [NPAD][512] bf16: [q | k1]
    const unsigned short* __restrict__ k2t,  // [ET][256] bf16
    const int* __restrict__ off, const unsigned int* __restrict__ pack,
    const unsigned short* __restrict__ scoresb, float* __restrict__ out)
{
    const int t = threadIdx.x;
    const int lane = t & 63;
    const int d = blockIdx.x * 4 + (t >> 6);
    if (d >= NN) return;

    const int beg = off[d], end = off[d + 1];
    if (beg == end) { out[(size_t)d * CC + lane] = 0.f; return; }

    // q[d] slice: 4 bf16 per lane
    uint2 qv = *reinterpret_cast<const uint2*>(qk + (size_t)d * 512 + lane * 4);
    float q0 = bf2f((unsigned short)(qv.x & 0xFFFF));
    float q1 = bf2f((unsigned short)(qv.x >> 16));
    float q2 = bf2f((unsigned short)(qv.y & 0xFFFF));
    float q3 = bf2f((unsigned short)(qv.y >> 16));

    // k2t in registers (static names; runtime-ty selected via cndmask)
    float e00, e01, e02, e03, e10, e11, e12, e13, e20, e21, e22, e23;
    {
        uint2 v0 = *reinterpret_cast<const uint2*>(k2t + 0 * HH + lane * 4);
        uint2 v1 = *reinterpret_cast<const uint2*>(k2t + 1 * HH + lane * 4);
        uint2 v2 = *reinterpret_cast<const uint2*>(k2t + 2 * HH + lane * 4);
        e00 = bf2f((unsigned short)(v0.x & 0xFFFF)); e01 = bf2f((unsigned short)(v0.x >> 16));
        e02 = bf2f((unsigned short)(v0.y & 0xFFFF)); e03 = bf2f((unsigned short)(v0.y >> 16));
        e10 = bf2f((unsigned short)(v1.x & 0xFFFF)); e11 = bf2f((unsigned short)(v1.x >> 16));
        e12 = bf2f((unsigned short)(v1.y & 0xFFFF)); e13 = bf2f((unsigned short)(v1.y >> 16));
        e20 = bf2f((unsigned short)(v2.x & 0xFFFF)); e21 = bf2f((unsigned short)(v2.x >> 16));
        e22 = bf2f((unsigned short)(v2.y & 0xFFFF)); e23 = bf2f((unsigned short)(v2.y >> 16));
    }

    // prologue: load edge `beg`
    unsigned int pk = pack[beg];
    int sr = pk & 0xFFFFFF;
    int ty = pk >> 24;
    uint2 kv  = *reinterpret_cast<const uint2*>(qk + (size_t)sr * 512 + 256 + lane * 4);
    float sc  = bf2f(scoresb[(size_t)sr * CC + lane]);

    float m = -INFINITY, s = 0.f, acc = 0.f;

    for (int i = beg; i < end; ++i) {
        // issue next edge's gathers before current edge's math
        int inext = (i + 1 < end) ? i + 1 : i;
        unsigned int pk1 = pack[inext];
        int sr1 = pk1 & 0xFFFFFF;
        int ty1 = pk1 >> 24;
        uint2 kv1 = *reinterpret_cast<const uint2*>(qk + (size_t)sr1 * 512 + 256 + lane * 4);
        float sc1 = bf2f(scoresb[(size_t)sr1 * CC + lane]);

        float k0 = bf2f((unsigned short)(kv.x & 0xFFFF));
        float k1 = bf2f((unsigned short)(kv.x >> 16));
        float k2 = bf2f((unsigned short)(kv.y & 0xFFFF));
        float k3 = bf2f((unsigned short)(kv.y >> 16));

        float f0 = (ty == 0) ? e00 : (ty == 1) ? e10 : e20;
        float f1 = (ty == 0) ? e01 : (ty == 1) ? e11 : e21;
        float f2 = (ty == 0) ? e02 : (ty == 1) ? e12 : e22;
        float f3 = (ty == 0) ? e03 : (ty == 1) ? e13 : e23;

        float p = q0 * (k0 + f0) + q1 * (k1 + f1) + q2 * (k2 + f2) + q3 * (k3 + f3);
        p += __shfl_xor(p, 1);
        p += __shfl_xor(p, 2);
        p += __shfl_xor(p, 4);
        p += __shfl_xor(p, 8);
        p += __shfl_xor(p, 16);
        p += __shfl_xor(p, 32);
        float a = p * 0.0625f;               // 1/sqrt(256)

        // branchless online softmax (first iter: exp(-inf)=0)
        float nm = fmaxf(m, a);
        float c_ = __expf(m - nm);
        float w_ = __expf(a - nm);
        s   = s * c_ + w_;
        acc = acc * c_ + w_ * sc;
        m = nm;

        kv = kv1; sc = sc1; ty = ty1;
    }
    out[(size_t)d * CC + lane] = acc / s;
}

extern "C" void kernel_launch(void* const* d_in, const int* in_sizes, int n_in,
                              void* d_out, int out_size, void* d_ws, size_t ws_size,
                              hipStream_t stream) {
    const float* embedding = (const float*)d_in[0];
    const float* scores    = (const float*)d_in[1];
    const int*   src       = (const int*)d_in[2];
    const int*   dst       = (const int*)d_in[3];
    const int*   typ       = (const int*)d_in[4];
    const float* W1  = (const float*)d_in[5];
    const float* b1  = (const float*)d_in[6];
    const float* W2  = (const float*)d_in[7];
    const float* b2  = (const float*)d_in[8];
    const float* ln_g = (const float*)d_in[9];
    const float* ln_b = (const float*)d_in[10];
    const float* Wl  = (const float*)d_in[11];
    const float* bl  = (const float*)d_in[12];
    const float* Wr  = (const float*)d_in[13];
    const float* br  = (const float*)d_in[14];
    const float* We  = (const float*)d_in[15];
    const float* be  = (const float*)d_in[16];
    const float* emb_table = (const float*)d_in[17];
    float* out = (float*)d_out;
    (void)in_sizes; (void)n_in; (void)out_size; (void)ws_size;

    // ---- workspace carve-up ----
    char* w = (char*)d_ws;
    auto take = [&](size_t bytes) {
        char* p = w;
        w += (bytes + 255) & ~(size_t)255;
        return p;
    };
    unsigned short* embA = (unsigned short*)take((size_t)NPAD * HH * 2);
    unsigned short* hpre = (unsigned short*)take((size_t)NPAD * HH * 2);
    unsigned short* qk   = (unsigned short*)take((size_t)NPAD * 512 * 2);
    unsigned short* Gch  = (unsigned short*)take((size_t)CHROWS * 4 * HH * 2);
    unsigned short* W1T  = (unsigned short*)take((size_t)4 * HH * HH * 2);
    unsigned short* W2T  = (unsigned short*)take((size_t)HH * 4 * HH * 2);
    unsigned short* WlrT = (unsigned short*)take((size_t)512 * HH * 2);
    unsigned short* k2t  = (unsigned short*)take(2048);
    unsigned short* scoresb = (unsigned short*)take((size_t)NN * CC * 2);
    float*          blr  = (float*)take(512 * 4);
    int*            cnt  = (int*)take((size_t)NN * 4);
    int*            offb = (int*)take((size_t)(NN + 1) * 4);
    int*            cur  = (int*)take((size_t)NN * 4);
    int*            bsum = (int*)take(256 * 4);
    unsigned int*   pack = (unsigned int*)take((size_t)EE * 4);

    // ---- CSR build ----
    hipMemsetAsync(cnt, 0, (size_t)NN * 4, stream);
    hist_kernel<<<(EE + 255) / 256, 256, 0, stream>>>(dst, cnt);
    scan_part<<<NB, 256, 0, stream>>>(cnt, offb, bsum);
    scan_sums<<<1, 256, 0, stream>>>(bsum);
    scan_add<<<NB, 256, 0, stream>>>(offb, bsum, cur);
    fill_kernel<<<(EE + 255) / 256, 256, 0, stream>>>(src, dst, typ, cur, pack);

    // ---- small prep ----
    k2_kernel<<<ETT, HH, 0, stream>>>(emb_table, We, be, k2t);
    concat_bias<<<1, 512, 0, stream>>>(bl, br, blr);
    f2bf4_kernel<<<(NN * HH / 4 + 255) / 256, 256, 0, stream>>>(embedding, embA, NN * HH / 4);
    f2bf4_kernel<<<(NN * CC / 4 + 255) / 256, 256, 0, stream>>>(scores, scoresb, NN * CC / 4);
    transpose_all<<<2560, 256, 0, stream>>>(W1, W2, Wl, Wr, W1T, W2T, WlrT);

    // ---- MLP: hpre = gelu(X@W1+b1)@W2+b2 (bf16), then LN in place ----
    for (int r0 = 0; r0 < NN; r0 += CHROWS) {
        int mr = (NN - r0 < CHROWS) ? (NN - r0) : CHROWS;
        int gy = (mr + 127) / 128;
        dim3 g1(4 * HH / 128, gy);
        mfma_gemm<true, true><<<g1, 256, 0, stream>>>(
            embA + (size_t)r0 * HH, W1T, b1, Gch, mr, HH, 4 * HH);
        dim3 g2(HH / 128, gy);
        mfma_gemm<false, true><<<g2, 256, 0, stream>>>(
            Gch, W2T, b2, hpre + (size_t)r0 * HH, mr, 4 * HH, HH);
    }
    ln_kernel<<<NN, 256, 0, stream>>>(hpre, ln_g, ln_b);

    // ---- q|k1 projection in one GEMM (Nc=512) ----
    dim3 gq(512 / 128, (NN + 127) / 128);
    mfma_gemm<false, true><<<gq, 256, 0, stream>>>(hpre, WlrT, blr, qk, NN, HH, 512);

    // ---- fused edge phase ----
    fused_edge_kernel<<<(NN + 3) / 4, 256, 0, stream>>>(qk, k2t, offb, pack, scoresb, out);
}

// Round 5
// 519.070 us; speedup vs baseline: 3.1822x; 1.0347x over previous
//
#include <hip/hip_runtime.h>
#include <math.h>

#define NN 50000
#define EE 800000
#define HH 256
#define CC 64
#define ETT 3
#define EFF 20
#define NPAD 50048          // NN rounded to 128
#define CHROWS 25088        // GEMM row chunk (multiple of 128)
#define NB 196              // scan blocks = ceil(NN/256)

typedef _Float16 f16x8 __attribute__((ext_vector_type(8)));
typedef _Float16 h2 __attribute__((ext_vector_type(2)));
typedef float f32x4 __attribute__((ext_vector_type(4)));

__device__ __forceinline__ float gelu_f(float x) {
    const float k0 = 0.7978845608028654f; // sqrt(2/pi)
    float x3 = x * x * x;
    return 0.5f * x * (1.0f + tanhf(k0 * (x + 0.044715f * x3)));
}

__device__ __forceinline__ unsigned short f2h(float x) {
    _Float16 h = (_Float16)x;
    return __builtin_bit_cast(unsigned short, h);
}

__device__ __forceinline__ float h2f_(unsigned short u) {
    return (float)__builtin_bit_cast(_Float16, u);
}

__device__ __forceinline__ h2 u2h2(unsigned int u) {
    return __builtin_bit_cast(h2, u);
}

__device__ __forceinline__ void gld_lds16(const void* g, void* l) {
    __builtin_amdgcn_global_load_lds(
        (const __attribute__((address_space(1))) unsigned int*)g,
        (__attribute__((address_space(3))) unsigned int*)l,
        16, 0, 0);
}

// ---------------------------------------------------------------------------
// C[M,Nc] = act(A_f16[M,K] @ BT_f16[Nc,K]^T + bias); 128x128 tile, BK=64,
// 4 waves, 16x16x32 f16 MFMA, global_load_lds, XOR-swizzled LDS.
// ---------------------------------------------------------------------------
template<bool GELU, bool OUT_F16>
__global__ __launch_bounds__(256) void mfma_gemm(
    const unsigned short* __restrict__ A,
    const unsigned short* __restrict__ BT,
    const float* __restrict__ bias,
    void* __restrict__ C,
    int M, int K, int Nc)
{
    __shared__ __align__(16) unsigned char lds[32768]; // A: [0,16K), B: [16K,32K)
    const int t    = threadIdx.x;
    const int lane = t & 63;
    const int wv   = t >> 6;
    const int wr   = wv >> 1, wc = wv & 1;
    const int row0 = blockIdx.y * 128;
    const int col0 = blockIdx.x * 128;

    f32x4 acc[4][4] = {};

    const int srow  = t >> 3;               // 0..31
    const int sslot = t & 7;
    const int schunk = sslot ^ (srow & 7);  // global k-chunk stored at this slot

    const unsigned short* Ab = A  + (size_t)row0 * K;
    const unsigned short* Bb = BT + (size_t)col0 * K;

    for (int k0 = 0; k0 < K; k0 += 64) {
        #pragma unroll
        for (int i = 0; i < 4; ++i)
            gld_lds16(Ab + (size_t)(i * 32 + srow) * K + k0 + schunk * 8,
                      &lds[i * 4096 + t * 16]);
        #pragma unroll
        for (int i = 0; i < 4; ++i)
            gld_lds16(Bb + (size_t)(i * 32 + srow) * K + k0 + schunk * 8,
                      &lds[16384 + i * 4096 + t * 16]);
        __syncthreads();

        #pragma unroll
        for (int kk = 0; kk < 2; ++kk) {
            f16x8 af[4], bf[4];
            #pragma unroll
            for (int m = 0; m < 4; ++m) {
                int r  = wr * 64 + m * 16 + (lane & 15);
                int ch = (kk * 4 + (lane >> 4)) ^ (r & 7);
                af[m] = *reinterpret_cast<const f16x8*>(&lds[r * 128 + ch * 16]);
            }
            #pragma unroll
            for (int n = 0; n < 4; ++n) {
                int r  = wc * 64 + n * 16 + (lane & 15);
                int ch = (kk * 4 + (lane >> 4)) ^ (r & 7);
                bf[n] = *reinterpret_cast<const f16x8*>(&lds[16384 + r * 128 + ch * 16]);
            }
            #pragma unroll
            for (int m = 0; m < 4; ++m)
                #pragma unroll
                for (int n = 0; n < 4; ++n)
                    acc[m][n] = __builtin_amdgcn_mfma_f32_16x16x32_f16(
                        af[m], bf[n], acc[m][n], 0, 0, 0);
        }
        __syncthreads();
    }

    #pragma unroll
    for (int n = 0; n < 4; ++n) {
        int col = col0 + wc * 64 + n * 16 + (lane & 15);
        float bv = bias[col];
        #pragma unroll
        for (int m = 0; m < 4; ++m) {
            #pragma unroll
            for (int rg = 0; rg < 4; ++rg) {
                int row = row0 + wr * 64 + m * 16 + (lane >> 4) * 4 + rg;
                if (row < M) {
                    float v = acc[m][n][rg] + bv;
                    if (GELU) v = gelu_f(v);
                    if (OUT_F16)
                        ((unsigned short*)C)[(size_t)row * Nc + col] = f2h(v);
                    else
                        ((float*)C)[(size_t)row * Nc + col] = v;
                }
            }
        }
    }
}

// LayerNorm in-place over rows of h [N,256] f16. One 256-thr block per row.
__global__ __launch_bounds__(256) void ln_kernel(
    unsigned short* __restrict__ h, const float* __restrict__ g,
    const float* __restrict__ b)
{
    int row = blockIdx.x;
    int t = threadIdx.x;
    float x = h2f_(h[(size_t)row * HH + t]);
    float s1 = x, s2 = x * x;
    #pragma unroll
    for (int off = 32; off; off >>= 1) {
        s1 += __shfl_down(s1, off);
        s2 += __shfl_down(s2, off);
    }
    __shared__ float r1[4], r2[4];
    int wid = t >> 6;
    if ((t & 63) == 0) { r1[wid] = s1; r2[wid] = s2; }
    __syncthreads();
    if (t == 0) {
        float a = 0.f, bb = 0.f;
        #pragma unroll
        for (int i = 0; i < 4; ++i) { a += r1[i]; bb += r2[i]; }
        r1[0] = a; r2[0] = bb;
    }
    __syncthreads();
    float mean = r1[0] * (1.0f / HH);
    float var  = r2[0] * (1.0f / HH) - mean * mean;
    float xn = (x - mean) * rsqrtf(var + 1e-5f);
    h[(size_t)row * HH + t] = f2h(xn * g[t] + b[t]);
}

// k2 per edge-type (f16 out): k2t[t][h] = gelu(emb_table[t]) @ We + be
__global__ void k2_kernel(const float* __restrict__ emb_table,
                          const float* __restrict__ We, const float* __restrict__ be,
                          unsigned short* __restrict__ k2t)
{
    int ty = blockIdx.x;
    int hc = threadIdx.x;
    float acc = be[hc];
    #pragma unroll
    for (int f = 0; f < EFF; ++f)
        acc += gelu_f(emb_table[ty * EFF + f]) * We[f * HH + hc];
    k2t[ty * HH + hc] = f2h(acc);
}

// fp32 -> f16, 4 elems/thread
__global__ void f2h4_kernel(const float* __restrict__ in,
                            unsigned short* __restrict__ out, int n4)
{
    int i = blockIdx.x * 256 + threadIdx.x;
    if (i >= n4) return;
    float4 v = reinterpret_cast<const float4*>(in)[i];
    ushort4 o;
    o.x = f2h(v.x); o.y = f2h(v.y); o.z = f2h(v.z); o.w = f2h(v.w);
    reinterpret_cast<ushort4*>(out)[i] = o;
}

// all 4 weight transposes in one launch; Wl scaled by 1/sqrt(H)=1/16
__global__ void transpose_all(const float* __restrict__ W1, const float* __restrict__ W2,
                              const float* __restrict__ Wl, const float* __restrict__ Wr,
                              unsigned short* __restrict__ W1T,
                              unsigned short* __restrict__ W2T,
                              unsigned short* __restrict__ WlrT)
{
    int gb = blockIdx.x;
    const float* in; unsigned short* outp; int R, Cc, o;
    float sc = 1.0f;
    if (gb < 1024)      { in = W1; outp = W1T;  R = HH;     Cc = 4 * HH; o = gb * 256 + threadIdx.x; }
    else if (gb < 2048) { in = W2; outp = W2T;  R = 4 * HH; Cc = HH;     o = (gb - 1024) * 256 + threadIdx.x; }
    else if (gb < 2304) { in = Wl; outp = WlrT; R = HH;     Cc = HH;     o = (gb - 2048) * 256 + threadIdx.x; sc = 0.0625f; }
    else                { in = Wr; outp = WlrT + HH * HH; R = HH; Cc = HH; o = (gb - 2304) * 256 + threadIdx.x; }
    int c = o / R, r = o - c * R;
    outp[o] = f2h(in[(size_t)r * Cc + c] * sc);
}

__global__ void concat_bias(const float* __restrict__ a, const float* __restrict__ b,
                            float* __restrict__ o)
{
    int t = threadIdx.x;
    o[t] = (t < HH) ? a[t] * 0.0625f : b[t - HH];
}

// ---- CSR build ----
__global__ void hist_kernel(const int* __restrict__ dst, int* __restrict__ cnt)
{
    int e = blockIdx.x * 256 + threadIdx.x;
    if (e < EE) atomicAdd(&cnt[dst[e]], 1);
}

// block-local exclusive scan of cnt -> off, block totals -> bsum
__global__ __launch_bounds__(256) void scan_part(
    const int* __restrict__ cnt, int* __restrict__ off, int* __restrict__ bsum)
{
    int b = blockIdx.x, t = threadIdx.x;
    int idx = b * 256 + t;
    int v = (idx < NN) ? cnt[idx] : 0;
    int inc = v;
    #pragma unroll
    for (int o = 1; o < 64; o <<= 1) {
        int u = __shfl_up(inc, o);
        if ((t & 63) >= o) inc += u;
    }
    __shared__ int wt[4];
    if ((t & 63) == 63) wt[t >> 6] = inc;
    __syncthreads();
    int wo = 0;
    #pragma unroll
    for (int w = 0; w < 4; ++w) if (w < (t >> 6)) wo += wt[w];
    if (idx < NN) off[idx] = wo + inc - v;
    if (t == 255) bsum[b] = wo + inc;
}

// exclusive scan of the NB block sums, in place (single block)
__global__ __launch_bounds__(256) void scan_sums(int* __restrict__ bsum)
{
    int t = threadIdx.x;
    int v = (t < NB) ? bsum[t] : 0;
    int inc = v;
    #pragma unroll
    for (int o = 1; o < 64; o <<= 1) {
        int u = __shfl_up(inc, o);
        if ((t & 63) >= o) inc += u;
    }
    __shared__ int wt[4];
    if ((t & 63) == 63) wt[t >> 6] = inc;
    __syncthreads();
    int wo = 0;
    #pragma unroll
    for (int w = 0; w < 4; ++w) if (w < (t >> 6)) wo += wt[w];
    if (t < NB) bsum[t] = wo + inc - v;
}

__global__ void scan_add(int* __restrict__ off, const int* __restrict__ bsum,
                         int* __restrict__ cur)
{
    int b = blockIdx.x, t = threadIdx.x;
    int idx = b * 256 + t;
    if (idx < NN) {
        int o = off[idx] + bsum[b];
        off[idx] = o;
        cur[idx] = o;
    }
    if (idx == 0) off[NN] = EE;
}

__global__ void fill_kernel(const int* __restrict__ src, const int* __restrict__ dst,
                            const int* __restrict__ typ, int* __restrict__ cur,
                            unsigned int* __restrict__ pack)
{
    int e = blockIdx.x * 256 + threadIdx.x;
    if (e >= EE) return;
    int pos = atomicAdd(&cur[dst[e]], 1);
    pack[pos] = (unsigned int)src[e] | ((unsigned int)typ[e] << 24);
}

// qe[d][ty] = <q_scaled[d], k2t[ty]>  (wave per node)
__global__ __launch_bounds__(256) void qe_kernel(
    const unsigned short* __restrict__ qk, const unsigned short* __restrict__ k2t,
    float* __restrict__ qe)
{
    const int t = threadIdx.x, lane = t & 63;
    const int d = blockIdx.x * 4 + (t >> 6);
    if (d >= NN) return;
    uint2 qv = *reinterpret_cast<const uint2*>(qk + (size_t)d * 512 + lane * 4);
    h2 qa = u2h2(qv.x), qb = u2h2(qv.y);
    uint2 v0 = *reinterpret_cast<const uint2*>(k2t + 0 * HH + lane * 4);
    uint2 v1 = *reinterpret_cast<const uint2*>(k2t + 1 * HH + lane * 4);
    uint2 v2 = *reinterpret_cast<const uint2*>(k2t + 2 * HH + lane * 4);
    h2 p0 = qa * u2h2(v0.x) + qb * u2h2(v0.y);
    h2 p1 = qa * u2h2(v1.x) + qb * u2h2(v1.y);
    h2 p2 = qa * u2h2(v2.x) + qb * u2h2(v2.y);
    float a0 = (float)p0[0] + (float)p0[1];
    float a1 = (float)p1[0] + (float)p1[1];
    float a2 = (float)p2[0] + (float)p2[1];
    #pragma unroll
    for (int o = 1; o < 64; o <<= 1) {
        a0 += __shfl_xor(a0, o);
        a1 += __shfl_xor(a1, o);
        a2 += __shfl_xor(a2, o);
    }
    float v = (lane == 0) ? a0 : (lane == 1) ? a1 : a2;
    if (lane < 3) qe[d * 4 + lane] = v;
}

// ---- fused per-dst attention: wave per node, 2-edge unrolled online softmax,
//      f16 packed dot, k2t folded into precomputed qe, depth-1 prefetch ----
__global__ __launch_bounds__(256) void fused_edge_kernel(
    const unsigned short* __restrict__ qk,      // f16 [NPAD][512]: [q/16 | k1]
    const float* __restrict__ qe,               // [NN][4] (3 used)
    const int* __restrict__ off, const unsigned int* __restrict__ pack,
    const unsigned short* __restrict__ scoresb, // f16 [NN][64]
    float* __restrict__ out)
{
    const int t = threadIdx.x, lane = t & 63;
    const int d = blockIdx.x * 4 + (t >> 6);
    if (d >= NN) return;
    const int beg = off[d], end = off[d + 1];
    if (beg == end) { out[(size_t)d * CC + lane] = 0.f; return; }

    uint2 qv = *reinterpret_cast<const uint2*>(qk + (size_t)d * 512 + lane * 4);
    h2 qa = u2h2(qv.x), qb = u2h2(qv.y);
    f32x4 qev = *reinterpret_cast<const f32x4*>(qe + d * 4);
    const float qe0 = qev[0], qe1 = qev[1], qe2 = qev[2];

    float m = -INFINITY, s = 0.f, acc = 0.f;

    uint2 kva = {}, kvb = {};
    float sca = 0.f, scb = 0.f;
    int tya = 0, tyb = 0;

    auto ldp = [&](int i, uint2& ka, uint2& kb, float& sa, float& sb,
                   int& ta, int& tb) {
        unsigned pk0 = pack[i];
        unsigned pk1 = pack[(i + 1 < end) ? i + 1 : i];
        int s0 = pk0 & 0xFFFFFF; ta = (int)(pk0 >> 24);
        int s1 = pk1 & 0xFFFFFF; tb = (int)(pk1 >> 24);
        ka = *reinterpret_cast<const uint2*>(qk + (size_t)s0 * 512 + 256 + lane * 4);
        kb = *reinterpret_cast<const uint2*>(qk + (size_t)s1 * 512 + 256 + lane * 4);
        sa = h2f_(scoresb[(size_t)s0 * CC + lane]);
        sb = h2f_(scoresb[(size_t)s1 * CC + lane]);
    };
    ldp(beg, kva, kvb, sca, scb, tya, tyb);

    for (int i = beg; i < end; i += 2) {
        uint2 nka = {}, nkb = {};
        float nsa = 0.f, nsb = 0.f;
        int nta = 0, ntb = 0;
        if (i + 2 < end) ldp(i + 2, nka, nkb, nsa, nsb, nta, ntb);

        h2 p0 = qa * u2h2(kva.x) + qb * u2h2(kva.y);
        h2 p1 = qa * u2h2(kvb.x) + qb * u2h2(kvb.y);
        float a0 = (float)p0[0] + (float)p0[1];
        float a1 = (float)p1[0] + (float)p1[1];
        #pragma unroll
        for (int o = 1; o < 64; o <<= 1) {
            a0 += __shfl_xor(a0, o);
            a1 += __shfl_xor(a1, o);
        }
        a0 += (tya == 0) ? qe0 : (tya == 1) ? qe1 : qe2;
        a1 += (tyb == 0) ? qe0 : (tyb == 1) ? qe1 : qe2;
        if (i + 1 >= end) a1 = -INFINITY;   // odd tail: zero weight

        float nm = fmaxf(m, fmaxf(a0, a1));
        float c_ = __expf(m - nm);
        float w0 = __expf(a0 - nm);
        float w1 = __expf(a1 - nm);
        s   = s * c_ + w0 + w1;
        acc = acc * c_ + w0 * sca + w1 * scb;
        m = nm;

        kva = nka; kvb = nkb; sca = nsa; scb = nsb; tya = nta; tyb = ntb;
    }
    out[(size_t)d * CC + lane] = acc / s;
}

extern "C" void kernel_launch(void* const* d_in, const int* in_sizes, int n_in,
                              void* d_out, int out_size, void* d_ws, size_t ws_size,
                              hipStream_t stream) {
    const float* embedding = (const float*)d_in[0];
    const float* scores    = (const float*)d_in[1];
    const int*   src       = (const int*)d_in[2];
    const int*   dst       = (const int*)d_in[3];
    const int*   typ       = (const int*)d_in[4];
    const float* W1  = (const float*)d_in[5];
    const float* b1  = (const float*)d_in[6];
    const float* W2  = (const float*)d_in[7];
    const float* b2  = (const float*)d_in[8];
    const float* ln_g = (const float*)d_in[9];
    const float* ln_b = (const float*)d_in[10];
    const float* Wl  = (const float*)d_in[11];
    const float* bl  = (const float*)d_in[12];
    const float* Wr  = (const float*)d_in[13];
    const float* br  = (const float*)d_in[14];
    const float* We  = (const float*)d_in[15];
    const float* be  = (const float*)d_in[16];
    const float* emb_table = (const float*)d_in[17];
    float* out = (float*)d_out;
    (void)in_sizes; (void)n_in; (void)out_size; (void)ws_size;

    // ---- workspace carve-up ----
    char* w = (char*)d_ws;
    auto take = [&](size_t bytes) {
        char* p = w;
        w += (bytes + 255) & ~(size_t)255;
        return p;
    };
    unsigned short* embA = (unsigned short*)take((size_t)NPAD * HH * 2);
    unsigned short* hpre = (unsigned short*)take((size_t)NPAD * HH * 2);
    unsigned short* qk   = (unsigned short*)take((size_t)NPAD * 512 * 2);
    unsigned short* Gch  = (unsigned short*)take((size_t)CHROWS * 4 * HH * 2);
    unsigned short* W1T  = (unsigned short*)take((size_t)4 * HH * HH * 2);
    unsigned short* W2T  = (unsigned short*)take((size_t)HH * 4 * HH * 2);
    unsigned short* WlrT = (unsigned short*)take((size_t)512 * HH * 2);
    unsigned short* k2t  = (unsigned short*)take(2048);
    unsigned short* scoresb = (unsigned short*)take((size_t)NN * CC * 2);
    float*          blr  = (float*)take(512 * 4);
    float*          qe   = (float*)take((size_t)NN * 4 * 4);
    int*            cnt  = (int*)take((size_t)NN * 4);
    int*            offb = (int*)take((size_t)(NN + 1) * 4);
    int*            cur  = (int*)take((size_t)NN * 4);
    int*            bsum = (int*)take(256 * 4);
    unsigned int*   pack = (unsigned int*)take((size_t)EE * 4);

    // ---- CSR build ----
    hipMemsetAsync(cnt, 0, (size_t)NN * 4, stream);
    hist_kernel<<<(EE + 255) / 256, 256, 0, stream>>>(dst, cnt);
    scan_part<<<NB, 256, 0, stream>>>(cnt, offb, bsum);
    scan_sums<<<1, 256, 0, stream>>>(bsum);
    scan_add<<<NB, 256, 0, stream>>>(offb, bsum, cur);
    fill_kernel<<<(EE + 255) / 256, 256, 0, stream>>>(src, dst, typ, cur, pack);

    // ---- small prep ----
    k2_kernel<<<ETT, HH, 0, stream>>>(emb_table, We, be, k2t);
    concat_bias<<<1, 512, 0, stream>>>(bl, br, blr);
    f2h4_kernel<<<(NN * HH / 4 + 255) / 256, 256, 0, stream>>>(embedding, embA, NN * HH / 4);
    f2h4_kernel<<<(NN * CC / 4 + 255) / 256, 256, 0, stream>>>(scores, scoresb, NN * CC / 4);
    transpose_all<<<2560, 256, 0, stream>>>(W1, W2, Wl, Wr, W1T, W2T, WlrT);

    // ---- MLP: hpre = gelu(X@W1+b1)@W2+b2 (f16), then LN in place ----
    for (int r0 = 0; r0 < NN; r0 += CHROWS) {
        int mr = (NN - r0 < CHROWS) ? (NN - r0) : CHROWS;
        int gy = (mr + 127) / 128;
        dim3 g1(4 * HH / 128, gy);
        mfma_gemm<true, true><<<g1, 256, 0, stream>>>(
            embA + (size_t)r0 * HH, W1T, b1, Gch, mr, HH, 4 * HH);
        dim3 g2(HH / 128, gy);
        mfma_gemm<false, true><<<g2, 256, 0, stream>>>(
            Gch, W2T, b2, hpre + (size_t)r0 * HH, mr, 4 * HH, HH);
    }
    ln_kernel<<<NN, 256, 0, stream>>>(hpre, ln_g, ln_b);

    // ---- q|k1 projection in one GEMM (Nc=512); q pre-scaled by 1/16 ----
    dim3 gq(512 / 128, (NN + 127) / 128);
    mfma_gemm<false, true><<<gq, 256, 0, stream>>>(hpre, WlrT, blr, qk, NN, HH, 512);

    // ---- qe table, then fused edge phase ----
    qe_kernel<<<(NN + 3) / 4, 256, 0, stream>>>(qk, k2t, qe);
    fused_edge_kernel<<<(NN + 3) / 4, 256, 0, stream>>>(qk, qe, offb, pack, scoresb, out);
}

// Round 6
// 412.951 us; speedup vs baseline: 3.9999x; 1.2570x over previous
//
#include <hip/hip_runtime.h>
#include <math.h>

#define NN 50000
#define EE 800000
#define HH 256
#define CC 64
#define NPAD 50048          // NN rounded to 128
#define CHROWS 25088        // GEMM row chunk (multiple of 128)
#define NB 196              // scan blocks = ceil(NN/256)
#define QSCALE 0.09016843798f   // (1/16) * log2(e): folds 1/sqrt(H) and exp->exp2

typedef _Float16 f16x8 __attribute__((ext_vector_type(8)));
typedef _Float16 h2 __attribute__((ext_vector_type(2)));
typedef float f32x4 __attribute__((ext_vector_type(4)));

__device__ __forceinline__ float gelu_f(float x) {
    const float k0 = 0.7978845608028654f; // sqrt(2/pi)
    float x3 = x * x * x;
    return 0.5f * x * (1.0f + tanhf(k0 * (x + 0.044715f * x3)));
}

__device__ __forceinline__ unsigned short f2h(float x) {
    _Float16 h = (_Float16)x;
    return __builtin_bit_cast(unsigned short, h);
}

__device__ __forceinline__ float h2f_(unsigned short u) {
    return (float)__builtin_bit_cast(_Float16, u);
}

__device__ __forceinline__ h2 u2h2(unsigned int u) {
    return __builtin_bit_cast(h2, u);
}

__device__ __forceinline__ void gld_lds16(const void* g, void* l) {
    __builtin_amdgcn_global_load_lds(
        (const __attribute__((address_space(1))) unsigned int*)g,
        (__attribute__((address_space(3))) unsigned int*)l,
        16, 0, 0);
}

// ---------------------------------------------------------------------------
// C[M,Nc] = act(A_f16[M,K] @ BT_f16[Nc,K]^T + bias); 128x128 tile, BK=64,
// 4 waves, 16x16x32 f16 MFMA, global_load_lds, XOR-swizzled LDS.
// STATS:  atomically accumulate per-row sum/sumsq of the output into st1/st2.
// LNFOLD: apply LayerNorm fold: out = inv*raw - inv*mu*u[col] + bias[col],
//         with mu/inv derived from row sums rs1/rs2 (of the LN input).
// ---------------------------------------------------------------------------
template<int ACT, bool OUT_F16, bool STATS, bool LNFOLD>
__global__ __launch_bounds__(256) void mfma_gemm(
    const unsigned short* __restrict__ A,
    const unsigned short* __restrict__ BT,
    const float* __restrict__ bias,
    void* __restrict__ C,
    int M, int K, int Nc,
    float* __restrict__ st1, float* __restrict__ st2,
    const float* __restrict__ rs1, const float* __restrict__ rs2,
    const float* __restrict__ uvec)
{
    __shared__ __align__(16) unsigned char lds[32768]; // A: [0,16K), B: [16K,32K)
    const int t    = threadIdx.x;
    const int lane = t & 63;
    const int wv   = t >> 6;
    const int wr   = wv >> 1, wc = wv & 1;
    const int row0 = blockIdx.y * 128;
    const int col0 = blockIdx.x * 128;

    f32x4 acc[4][4] = {};

    const int srow  = t >> 3;               // 0..31
    const int sslot = t & 7;
    const int schunk = sslot ^ (srow & 7);  // global k-chunk stored at this slot

    const unsigned short* Ab = A  + (size_t)row0 * K;
    const unsigned short* Bb = BT + (size_t)col0 * K;

    for (int k0 = 0; k0 < K; k0 += 64) {
        #pragma unroll
        for (int i = 0; i < 4; ++i)
            gld_lds16(Ab + (size_t)(i * 32 + srow) * K + k0 + schunk * 8,
                      &lds[i * 4096 + t * 16]);
        #pragma unroll
        for (int i = 0; i < 4; ++i)
            gld_lds16(Bb + (size_t)(i * 32 + srow) * K + k0 + schunk * 8,
                      &lds[16384 + i * 4096 + t * 16]);
        __syncthreads();

        #pragma unroll
        for (int kk = 0; kk < 2; ++kk) {
            f16x8 af[4], bf[4];
            #pragma unroll
            for (int m = 0; m < 4; ++m) {
                int r  = wr * 64 + m * 16 + (lane & 15);
                int ch = (kk * 4 + (lane >> 4)) ^ (r & 7);
                af[m] = *reinterpret_cast<const f16x8*>(&lds[r * 128 + ch * 16]);
            }
            #pragma unroll
            for (int n = 0; n < 4; ++n) {
                int r  = wc * 64 + n * 16 + (lane & 15);
                int ch = (kk * 4 + (lane >> 4)) ^ (r & 7);
                bf[n] = *reinterpret_cast<const f16x8*>(&lds[16384 + r * 128 + ch * 16]);
            }
            #pragma unroll
            for (int m = 0; m < 4; ++m)
                #pragma unroll
                for (int n = 0; n < 4; ++n)
                    acc[m][n] = __builtin_amdgcn_mfma_f32_16x16x32_f16(
                        af[m], bf[n], acc[m][n], 0, 0, 0);
        }
        __syncthreads();
    }

    float bv[4], uv_[4];
    #pragma unroll
    for (int n = 0; n < 4; ++n) {
        int col = col0 + wc * 64 + n * 16 + (lane & 15);
        bv[n] = bias[col];
        if (LNFOLD) uv_[n] = uvec[col];
    }

    #pragma unroll
    for (int m = 0; m < 4; ++m) {
        #pragma unroll
        for (int rg = 0; rg < 4; ++rg) {
            int row = row0 + wr * 64 + m * 16 + (lane >> 4) * 4 + rg;
            float inv = 0.f, nmu = 0.f;
            if (LNFOLD) {
                float S1 = rs1[row], S2 = rs2[row];
                float mu = S1 * (1.0f / HH);
                float var = S2 * (1.0f / HH) - mu * mu;
                inv = rsqrtf(var + 1e-5f);
                nmu = inv * mu;
            }
            float s1l = 0.f, s2l = 0.f;
            #pragma unroll
            for (int n = 0; n < 4; ++n) {
                float v;
                if (LNFOLD) v = fmaf(inv, acc[m][n][rg], fmaf(-nmu, uv_[n], bv[n]));
                else        v = acc[m][n][rg] + bv[n];
                if (ACT) v = gelu_f(v);
                if (STATS) { s1l += v; s2l += v * v; }
                if (row < M) {
                    int col = col0 + wc * 64 + n * 16 + (lane & 15);
                    if (OUT_F16) ((unsigned short*)C)[(size_t)row * Nc + col] = f2h(v);
                    else         ((float*)C)[(size_t)row * Nc + col] = v;
                }
            }
            if (STATS) {
                #pragma unroll
                for (int o = 1; o < 16; o <<= 1) {
                    s1l += __shfl_xor(s1l, o);
                    s2l += __shfl_xor(s2l, o);
                }
                if ((lane & 15) == 0 && row < M) {
                    atomicAdd(&st1[row], s1l);
                    atomicAdd(&st2[row], s2l);
                }
            }
        }
    }
}

// ---------------------------------------------------------------------------
// prep mega-kernel: f2h(embedding), f2h(scores), W1T, W2T, WlrT (g-folded,
// q-half scaled by QSCALE), k2 table, u/v fold vectors — one launch.
// ---------------------------------------------------------------------------
#define PB0 12500                 // embedding f2h   (NN*HH/4/256)
#define PB1 (PB0 + 3125)          // scores f2h
#define PB2 (PB1 + 1024)          // W1T
#define PB3 (PB2 + 1024)          // W2T
#define PB4 (PB3 + 256)           // WlT'
#define PB5 (PB4 + 256)           // WrT'
#define PB6 (PB5 + 3)             // k2
#define PB7 (PB6 + 2)             // u/v
__global__ __launch_bounds__(256) void prep_kernel(
    const float* __restrict__ embedding, const float* __restrict__ scores,
    const float* __restrict__ W1, const float* __restrict__ W2,
    const float* __restrict__ Wl, const float* __restrict__ Wr,
    const float* __restrict__ ln_g, const float* __restrict__ ln_b,
    const float* __restrict__ bl, const float* __restrict__ br,
    const float* __restrict__ We, const float* __restrict__ be,
    const float* __restrict__ emb_table,
    unsigned short* __restrict__ embA, unsigned short* __restrict__ scoresb,
    unsigned short* __restrict__ W1T, unsigned short* __restrict__ W2T,
    unsigned short* __restrict__ WlrT, unsigned short* __restrict__ k2t,
    float* __restrict__ uvec, float* __restrict__ vvec)
{
    const int gb = blockIdx.x, t = threadIdx.x;
    if (gb < PB0) {
        int i = gb * 256 + t;
        float4 v = reinterpret_cast<const float4*>(embedding)[i];
        ushort4 o; o.x = f2h(v.x); o.y = f2h(v.y); o.z = f2h(v.z); o.w = f2h(v.w);
        reinterpret_cast<ushort4*>(embA)[i] = o;
    } else if (gb < PB1) {
        int i = (gb - PB0) * 256 + t;
        float4 v = reinterpret_cast<const float4*>(scores)[i];
        ushort4 o; o.x = f2h(v.x); o.y = f2h(v.y); o.z = f2h(v.z); o.w = f2h(v.w);
        reinterpret_cast<ushort4*>(scoresb)[i] = o;
    } else if (gb < PB2) {
        int o = (gb - PB1) * 256 + t;          // W1T[c][r], c=o>>8
        int c = o >> 8, r = o & 255;
        W1T[o] = f2h(W1[r * 1024 + c]);
    } else if (gb < PB3) {
        int o = (gb - PB2) * 256 + t;          // W2T[c][r], c=o>>10
        int c = o >> 10, r = o & 1023;
        W2T[o] = f2h(W2[r * 256 + c]);
    } else if (gb < PB4) {
        int o = (gb - PB3) * 256 + t;
        int c = o >> 8, r = o & 255;
        WlrT[o] = f2h(Wl[r * 256 + c] * ln_g[r] * QSCALE);
    } else if (gb < PB5) {
        int o = (gb - PB4) * 256 + t;
        int c = o >> 8, r = o & 255;
        WlrT[65536 + o] = f2h(Wr[r * 256 + c] * ln_g[r]);
    } else if (gb < PB6) {
        int ty = gb - PB5;
        float a = be[t];
        #pragma unroll
        for (int f = 0; f < 20; ++f)
            a += gelu_f(emb_table[ty * 20 + f]) * We[f * 256 + t];
        k2t[ty * 256 + t] = f2h(a);
    } else {
        int c = (gb - PB6) * 256 + t;          // 0..511
        int cc = c & 255;
        const float* W = (c < 256) ? Wl : Wr;
        float u = 0.f, v = 0.f;
        for (int j = 0; j < 256; ++j) {
            float w = W[j * 256 + cc];
            u += ln_g[j] * w;
            v += ln_b[j] * w;
        }
        float sc = (c < 256) ? QSCALE : 1.0f;
        uvec[c] = u * sc;
        vvec[c] = (v + ((c < 256) ? bl[cc] : br[cc])) * sc;
    }
}

// ---- CSR build ----
__global__ void hist_kernel(const int* __restrict__ dst, int* __restrict__ cnt)
{
    int e = blockIdx.x * 256 + threadIdx.x;
    if (e < EE) atomicAdd(&cnt[dst[e]], 1);
}

__global__ __launch_bounds__(256) void scan_part(
    const int* __restrict__ cnt, int* __restrict__ off, int* __restrict__ bsum)
{
    int b = blockIdx.x, t = threadIdx.x;
    int idx = b * 256 + t;
    int v = (idx < NN) ? cnt[idx] : 0;
    int inc = v;
    #pragma unroll
    for (int o = 1; o < 64; o <<= 1) {
        int u = __shfl_up(inc, o);
        if ((t & 63) >= o) inc += u;
    }
    __shared__ int wt[4];
    if ((t & 63) == 63) wt[t >> 6] = inc;
    __syncthreads();
    int wo = 0;
    #pragma unroll
    for (int w = 0; w < 4; ++w) if (w < (t >> 6)) wo += wt[w];
    if (idx < NN) off[idx] = wo + inc - v;
    if (t == 255) bsum[b] = wo + inc;
}

__global__ __launch_bounds__(256) void scan_sums(int* __restrict__ bsum)
{
    int t = threadIdx.x;
    int v = (t < NB) ? bsum[t] : 0;
    int inc = v;
    #pragma unroll
    for (int o = 1; o < 64; o <<= 1) {
        int u = __shfl_up(inc, o);
        if ((t & 63) >= o) inc += u;
    }
    __shared__ int wt[4];
    if ((t & 63) == 63) wt[t >> 6] = inc;
    __syncthreads();
    int wo = 0;
    #pragma unroll
    for (int w = 0; w < 4; ++w) if (w < (t >> 6)) wo += wt[w];
    if (t < NB) bsum[t] = wo + inc - v;
}

__global__ void scan_add(int* __restrict__ off, const int* __restrict__ bsum,
                         int* __restrict__ cur)
{
    int b = blockIdx.x, t = threadIdx.x;
    int idx = b * 256 + t;
    if (idx < NN) {
        int o = off[idx] + bsum[b];
        off[idx] = o;
        cur[idx] = o;
    }
    if (idx == 0) off[NN] = EE;
}

// pack entry = (src * 1024) | ty  -> byte offset of the qk row, type in low 2 bits
__global__ void fill_kernel(const int* __restrict__ src, const int* __restrict__ dst,
                            const int* __restrict__ typ, int* __restrict__ cur,
                            unsigned int* __restrict__ pack)
{
    int e = blockIdx.x * 256 + threadIdx.x;
    if (e == 0) pack[EE] = 0;     // pad slot for unconditional uint2 reads
    if (e >= EE) return;
    int pos = atomicAdd(&cur[dst[e]], 1);
    pack[pos] = ((unsigned int)src[e] << 10) | (unsigned int)typ[e];
}

// ---------------------------------------------------------------------------
// fused per-dst attention: one wave per node; 2 edges in flight with
// 32-lanes-per-edge dot (shared 5-level reduce), exp2-domain online softmax,
// qe (q . k2t[ty]) computed once in the prologue, depth-1 prefetch.
// ---------------------------------------------------------------------------
__global__ __launch_bounds__(256) void fused_edge_kernel(
    const unsigned short* __restrict__ qk,      // f16 [NPAD][512]: [q*QSCALE | k1]
    const unsigned short* __restrict__ k2t,     // f16 [3][256]
    const int* __restrict__ off, const unsigned int* __restrict__ pack,
    const unsigned short* __restrict__ scoresb, // f16 [NN][64]
    float* __restrict__ out)
{
    const int t = threadIdx.x, lane = t & 63;
    const int sub = lane & 31;
    const int g = lane >> 5;
    const int d = blockIdx.x * 4 + (t >> 6);
    if (d >= NN) return;
    const int beg = off[d], end = off[d + 1];
    if (beg == end) { out[(size_t)d * CC + lane] = 0.f; return; }

    const char* qkb = (const char*)qk;

    // q slice: 8 f16 at dims [sub*8, sub*8+8) (duplicated across lane halves)
    uint4 qv = *reinterpret_cast<const uint4*>(qkb + (size_t)d * 1024 + sub * 16);
    h2 q0 = u2h2(qv.x), q1 = u2h2(qv.y), q2 = u2h2(qv.z), q3 = u2h2(qv.w);

    // qe[ty] = q . k2t[ty] (already exp2-domain scaled via q)
    float qe0, qe1, qe2;
    {
        uint4 k0v = *reinterpret_cast<const uint4*>((const char*)k2t + 0 * 512 + sub * 16);
        uint4 k1v = *reinterpret_cast<const uint4*>((const char*)k2t + 1 * 512 + sub * 16);
        uint4 k2v = *reinterpret_cast<const uint4*>((const char*)k2t + 2 * 512 + sub * 16);
        h2 p0 = q0 * u2h2(k0v.x) + q1 * u2h2(k0v.y) + q2 * u2h2(k0v.z) + q3 * u2h2(k0v.w);
        h2 p1 = q0 * u2h2(k1v.x) + q1 * u2h2(k1v.y) + q2 * u2h2(k1v.z) + q3 * u2h2(k1v.w);
        h2 p2 = q0 * u2h2(k2v.x) + q1 * u2h2(k2v.y) + q2 * u2h2(k2v.z) + q3 * u2h2(k2v.w);
        qe0 = (float)p0[0] + (float)p0[1];
        qe1 = (float)p1[0] + (float)p1[1];
        qe2 = (float)p2[0] + (float)p2[1];
        #pragma unroll
        for (int o = 1; o < 32; o <<= 1) {
            qe0 += __shfl_xor(qe0, o);
            qe1 += __shfl_xor(qe1, o);
            qe2 += __shfl_xor(qe2, o);
        }
    }

    // prologue: pair {beg, beg+1}
    uint2 pp = *reinterpret_cast<const uint2*>(&pack[beg]);
    unsigned pkA = pp.x, pkB = pp.y;
    uint4 kv = *reinterpret_cast<const uint4*>(qkb + ((g ? pkB : pkA) & ~3u) + 512 + sub * 16);
    float scA = h2f_(scoresb[((pkA & ~3u) >> 4) + lane]);
    float scB = h2f_(scoresb[((pkB & ~3u) >> 4) + lane]);

    float m = -INFINITY, s = 0.f, acc = 0.f;

    for (int i = beg; i < end; i += 2) {
        int inext = (i + 2 < end) ? i + 2 : i;
        uint2 np = *reinterpret_cast<const uint2*>(&pack[inext]);
        uint4 nkv = *reinterpret_cast<const uint4*>(qkb + ((g ? np.y : np.x) & ~3u) + 512 + sub * 16);
        float nsA = h2f_(scoresb[((np.x & ~3u) >> 4) + lane]);
        float nsB = h2f_(scoresb[((np.y & ~3u) >> 4) + lane]);

        h2 p = q0 * u2h2(kv.x) + q1 * u2h2(kv.y) + q2 * u2h2(kv.z) + q3 * u2h2(kv.w);
        float a = (float)p[0] + (float)p[1];
        #pragma unroll
        for (int o = 1; o < 32; o <<= 1) a += __shfl_xor(a, o);
        float other = __shfl_xor(a, 32);
        float aA = g ? other : a;
        float aB = g ? a : other;
        int tyA = pkA & 3, tyB = pkB & 3;
        aA += (tyA == 0) ? qe0 : (tyA == 1) ? qe1 : qe2;
        aB += (tyB == 0) ? qe0 : (tyB == 1) ? qe1 : qe2;
        if (i + 1 >= end) aB = -INFINITY;     // odd tail

        float nm = fmaxf(m, fmaxf(aA, aB));
        float c_ = exp2f(m - nm);             // first iter: exp2(-inf)=0
        float w0 = exp2f(aA - nm);
        float w1 = exp2f(aB - nm);
        s = s * c_ + w0 + w1;
        acc = fmaf(acc, c_, fmaf(w0, scA, w1 * scB));
        m = nm;

        pkA = np.x; pkB = np.y; kv = nkv; scA = nsA; scB = nsB;
    }
    out[(size_t)d * CC + lane] = acc / s;
}

extern "C" void kernel_launch(void* const* d_in, const int* in_sizes, int n_in,
                              void* d_out, int out_size, void* d_ws, size_t ws_size,
                              hipStream_t stream) {
    const float* embedding = (const float*)d_in[0];
    const float* scores    = (const float*)d_in[1];
    const int*   src       = (const int*)d_in[2];
    const int*   dst       = (const int*)d_in[3];
    const int*   typ       = (const int*)d_in[4];
    const float* W1  = (const float*)d_in[5];
    const float* b1  = (const float*)d_in[6];
    const float* W2  = (const float*)d_in[7];
    const float* b2  = (const float*)d_in[8];
    const float* ln_g = (const float*)d_in[9];
    const float* ln_b = (const float*)d_in[10];
    const float* Wl  = (const float*)d_in[11];
    const float* bl  = (const float*)d_in[12];
    const float* Wr  = (const float*)d_in[13];
    const float* br  = (const float*)d_in[14];
    const float* We  = (const float*)d_in[15];
    const float* be  = (const float*)d_in[16];
    const float* emb_table = (const float*)d_in[17];
    float* out = (float*)d_out;
    (void)in_sizes; (void)n_in; (void)out_size; (void)ws_size;

    // ---- workspace carve-up (256-aligned chunks) ----
    char* w = (char*)d_ws;
    auto take = [&](size_t bytes) {
        char* p = w;
        w += (bytes + 255) & ~(size_t)255;
        return p;
    };
    unsigned short* embA = (unsigned short*)take((size_t)NPAD * HH * 2);
    unsigned short* hpre = (unsigned short*)take((size_t)NPAD * HH * 2);
    unsigned short* qk   = (unsigned short*)take((size_t)NPAD * 512 * 2);
    unsigned short* Gch  = (unsigned short*)take((size_t)CHROWS * 4 * HH * 2);
    unsigned short* W1T  = (unsigned short*)take((size_t)4 * HH * HH * 2);
    unsigned short* W2T  = (unsigned short*)take((size_t)HH * 4 * HH * 2);
    unsigned short* WlrT = (unsigned short*)take((size_t)512 * HH * 2);
    unsigned short* k2t  = (unsigned short*)take(2048);
    unsigned short* scoresb = (unsigned short*)take((size_t)NN * CC * 2);
    float*          uvec = (float*)take(512 * 4);
    float*          vvec = (float*)take(512 * 4);
    int*            cnt  = (int*)take((size_t)NPAD * 4);   // NPAD*4 is 256-aligned
    float*          st1  = (float*)take((size_t)NPAD * 4); // contiguous with cnt
    float*          st2  = (float*)take((size_t)NPAD * 4); // contiguous with st1
    int*            offb = (int*)take((size_t)(NN + 1) * 4);
    int*            cur  = (int*)take((size_t)NN * 4);
    int*            bsum = (int*)take(256 * 4);
    unsigned int*   pack = (unsigned int*)take((size_t)EE * 4 + 16);

    // zero cnt + st1 + st2 in one memset (contiguous NPAD-sized chunks)
    hipMemsetAsync(cnt, 0, (size_t)3 * NPAD * 4, stream);

    // ---- one prep launch: conversions, transposes, k2, u/v ----
    prep_kernel<<<PB7, 256, 0, stream>>>(
        embedding, scores, W1, W2, Wl, Wr, ln_g, ln_b, bl, br, We, be, emb_table,
        embA, scoresb, W1T, W2T, WlrT, k2t, uvec, vvec);

    // ---- CSR build ----
    hist_kernel<<<(EE + 255) / 256, 256, 0, stream>>>(dst, cnt);
    scan_part<<<NB, 256, 0, stream>>>(cnt, offb, bsum);
    scan_sums<<<1, 256, 0, stream>>>(bsum);
    scan_add<<<NB, 256, 0, stream>>>(offb, bsum, cur);
    fill_kernel<<<(EE + 255) / 256, 256, 0, stream>>>(src, dst, typ, cur, pack);

    // ---- MLP: hpre = gelu(X@W1+b1)@W2+b2 (f16), W2 also emits row stats ----
    for (int r0 = 0; r0 < NN; r0 += CHROWS) {
        int mr = (NN - r0 < CHROWS) ? (NN - r0) : CHROWS;
        int gy = (mr + 127) / 128;
        dim3 g1(4 * HH / 128, gy);
        mfma_gemm<1, true, false, false><<<g1, 256, 0, stream>>>(
            embA + (size_t)r0 * HH, W1T, b1, Gch, mr, HH, 4 * HH,
            nullptr, nullptr, nullptr, nullptr, nullptr);
        dim3 g2(HH / 128, gy);
        mfma_gemm<0, true, true, false><<<g2, 256, 0, stream>>>(
            Gch, W2T, b2, hpre + (size_t)r0 * HH, mr, 4 * HH, HH,
            st1 + r0, st2 + r0, nullptr, nullptr, nullptr);
    }

    // ---- q|k1 projection with fused LayerNorm (LN folded into epilogue) ----
    dim3 gq(512 / 128, (NN + 127) / 128);
    mfma_gemm<0, true, false, true><<<gq, 256, 0, stream>>>(
        hpre, WlrT, vvec, qk, NN, HH, 512,
        nullptr, nullptr, st1, st2, uvec);

    // ---- fused edge phase ----
    fused_edge_kernel<<<(NN + 3) / 4, 256, 0, stream>>>(qk, k2t, offb, pack, scoresb, out);
}